// Round 1
// baseline (1083.903 us; speedup 1.0000x reference)
//
#include <hip/hip_runtime.h>
#include <hip/hip_bf16.h>

#define B_   8
#define NQ_  1000
#define D_   256
#define NH_  8
#define L_   4
#define P_   4
#define DFF_ 1024
#define HD_  32
#define S_   21760
#define NTOK (B_*NQ_)

// ---------- helpers ----------
__device__ inline unsigned short f32_to_bf16_bits(float f) {
    unsigned int u = __float_as_uint(f);
    unsigned int rounding = 0x7FFFu + ((u >> 16) & 1u);
    u += rounding;
    return (unsigned short)(u >> 16);
}
__device__ inline float bf16_bits_to_f32(unsigned short b) {
    return __uint_as_float(((unsigned int)b) << 16);
}

// ---------- GEMM: C[M,N] = (A (+A2)) @ Bm[K,N] + bias, optional ReLU, optional bf16 out ----------
// Tile 64x64, BK=16, 256 threads, 4x4 per thread.
template<bool ADD_A2, bool RELU, bool BF16_OUT>
__global__ __launch_bounds__(256) void gemm_k(const float* __restrict__ A,
                                              const float* __restrict__ A2,
                                              const float* __restrict__ Bm,
                                              const float* __restrict__ bias,
                                              float* __restrict__ Cf,
                                              unsigned short* __restrict__ Cb,
                                              int M, int N, int K)
{
    __shared__ float As[16][64];
    __shared__ float Bs[16][64];
    const int tid = threadIdx.x;
    const int tx = tid & 15, ty = tid >> 4;
    const int m0 = blockIdx.x * 64, n0 = blockIdx.y * 64;

    // A-load mapping: thread t loads float4 of row (t>>2), k-chunk (t&3)*4
    const int lm = tid >> 2;
    const int lk = (tid & 3) * 4;
    // B-load mapping: thread t loads 4 scalars: rows bk0..bk0+3, col bn
    const int bn  = tid & 63;
    const int bk0 = (tid >> 6) * 4;

    float acc[4][4] = {};

    for (int k0 = 0; k0 < K; k0 += 16) {
        float4 av = *reinterpret_cast<const float4*>(A + (size_t)(m0 + lm) * K + k0 + lk);
        if (ADD_A2) {
            float4 a2 = *reinterpret_cast<const float4*>(A2 + (size_t)(m0 + lm) * K + k0 + lk);
            av.x += a2.x; av.y += a2.y; av.z += a2.z; av.w += a2.w;
        }
        float bv[4];
        #pragma unroll
        for (int i = 0; i < 4; i++)
            bv[i] = Bm[(size_t)(k0 + bk0 + i) * N + n0 + bn];

        __syncthreads();
        As[lk + 0][lm] = av.x;
        As[lk + 1][lm] = av.y;
        As[lk + 2][lm] = av.z;
        As[lk + 3][lm] = av.w;
        #pragma unroll
        for (int i = 0; i < 4; i++) Bs[bk0 + i][bn] = bv[i];
        __syncthreads();

        #pragma unroll
        for (int kk = 0; kk < 16; kk++) {
            float4 a = *reinterpret_cast<const float4*>(&As[kk][ty * 4]);
            float4 b = *reinterpret_cast<const float4*>(&Bs[kk][tx * 4]);
            acc[0][0] += a.x * b.x; acc[0][1] += a.x * b.y; acc[0][2] += a.x * b.z; acc[0][3] += a.x * b.w;
            acc[1][0] += a.y * b.x; acc[1][1] += a.y * b.y; acc[1][2] += a.y * b.z; acc[1][3] += a.y * b.w;
            acc[2][0] += a.z * b.x; acc[2][1] += a.z * b.y; acc[2][2] += a.z * b.z; acc[2][3] += a.z * b.w;
            acc[3][0] += a.w * b.x; acc[3][1] += a.w * b.y; acc[3][2] += a.w * b.z; acc[3][3] += a.w * b.w;
        }
    }

    const int col0 = n0 + tx * 4;
    float4 bias4 = *reinterpret_cast<const float4*>(bias + col0);
    #pragma unroll
    for (int i = 0; i < 4; i++) {
        int row = m0 + ty * 4 + i;
        float c0 = acc[i][0] + bias4.x;
        float c1 = acc[i][1] + bias4.y;
        float c2 = acc[i][2] + bias4.z;
        float c3 = acc[i][3] + bias4.w;
        if (RELU) {
            c0 = fmaxf(c0, 0.f); c1 = fmaxf(c1, 0.f);
            c2 = fmaxf(c2, 0.f); c3 = fmaxf(c3, 0.f);
        }
        if constexpr (BF16_OUT) {
            ushort4 pk;
            pk.x = f32_to_bf16_bits(c0); pk.y = f32_to_bf16_bits(c1);
            pk.z = f32_to_bf16_bits(c2); pk.w = f32_to_bf16_bits(c3);
            *reinterpret_cast<ushort4*>(Cb + (size_t)row * N + col0) = pk;
        } else {
            float4 o = {c0, c1, c2, c3};
            *reinterpret_cast<float4*>(Cf + (size_t)row * N + col0) = o;
        }
    }
}

// ---------- self-attention: per-thread row, online softmax ----------
// grid (4, NH, B), block 256. Each thread = one query row for head h, batch b.
__global__ __launch_bounds__(256) void attn_k(const float* __restrict__ qm,
                                              const float* __restrict__ km,
                                              const float* __restrict__ vm,
                                              float* __restrict__ om)
{
    const int b = blockIdx.z, h = blockIdx.y;
    const int r = blockIdx.x * 256 + threadIdx.x;
    const bool active = r < NQ_;
    const int rc = active ? r : (NQ_ - 1);
    const float scale = 0.17677669529663687f;  // 1/sqrt(32)

    float qreg[HD_];
    {
        const float* qrow = qm + ((size_t)(b * NQ_ + rc)) * D_ + h * HD_;
        #pragma unroll
        for (int i = 0; i < HD_ / 4; i++) {
            float4 t = reinterpret_cast<const float4*>(qrow)[i];
            qreg[4 * i + 0] = t.x; qreg[4 * i + 1] = t.y;
            qreg[4 * i + 2] = t.z; qreg[4 * i + 3] = t.w;
        }
    }

    __shared__ float Ks[64][HD_];
    __shared__ float Vs[64][HD_];

    float m = -1e30f, s = 0.f;
    float acc[HD_];
    #pragma unroll
    for (int c = 0; c < HD_; c++) acc[c] = 0.f;

    for (int kt = 0; kt < 16; kt++) {
        const int nrows = min(64, NQ_ - kt * 64);
        __syncthreads();
        for (int e = threadIdx.x; e < nrows * HD_; e += 256) {
            int row = e >> 5, c = e & 31;
            size_t g = ((size_t)(b * NQ_ + kt * 64 + row)) * D_ + h * HD_ + c;
            Ks[row][c] = km[g];
            Vs[row][c] = vm[g];
        }
        __syncthreads();

        for (int j = 0; j < nrows; j++) {
            float sc = 0.f;
            #pragma unroll
            for (int c = 0; c < HD_; c++) sc += qreg[c] * Ks[j][c];
            sc *= scale;
            if (sc > m) {
                float f = __expf(m - sc);
                s *= f;
                #pragma unroll
                for (int c = 0; c < HD_; c++) acc[c] *= f;
                m = sc;
            }
            float w = __expf(sc - m);
            s += w;
            #pragma unroll
            for (int c = 0; c < HD_; c++) acc[c] += w * Vs[j][c];
        }
    }

    if (active) {
        float inv = 1.f / s;
        float* orow = om + ((size_t)(b * NQ_ + r)) * D_ + h * HD_;
        #pragma unroll
        for (int i = 0; i < HD_ / 4; i++) {
            float4 o = {acc[4 * i] * inv, acc[4 * i + 1] * inv,
                        acc[4 * i + 2] * inv, acc[4 * i + 3] * inv};
            reinterpret_cast<float4*>(orow)[i] = o;
        }
    }
}

// ---------- LayerNorm(out = LN(a + b) * g + be) over rows of 256 ----------
__global__ __launch_bounds__(256) void ln_k(const float* __restrict__ a,
                                            const float* __restrict__ bsum,
                                            const float* __restrict__ g,
                                            const float* __restrict__ be,
                                            float* __restrict__ out)
{
    const int wave = threadIdx.x >> 6, lane = threadIdx.x & 63;
    const int row = blockIdx.x * 4 + wave;
    float4 xa = reinterpret_cast<const float4*>(a + (size_t)row * 256)[lane];
    float4 xb = reinterpret_cast<const float4*>(bsum + (size_t)row * 256)[lane];
    float4 x = {xa.x + xb.x, xa.y + xb.y, xa.z + xb.z, xa.w + xb.w};
    float s  = x.x + x.y + x.z + x.w;
    float ss = x.x * x.x + x.y * x.y + x.z * x.z + x.w * x.w;
    #pragma unroll
    for (int off = 32; off > 0; off >>= 1) {
        s  += __shfl_xor(s, off);
        ss += __shfl_xor(ss, off);
    }
    float mu  = s * (1.f / 256.f);
    float var = ss * (1.f / 256.f) - mu * mu;
    float rstd = rsqrtf(var + 1e-5f);
    float4 gv = reinterpret_cast<const float4*>(g)[lane];
    float4 bv = reinterpret_cast<const float4*>(be)[lane];
    float4 o = {(x.x - mu) * rstd * gv.x + bv.x,
                (x.y - mu) * rstd * gv.y + bv.y,
                (x.z - mu) * rstd * gv.z + bv.z,
                (x.w - mu) * rstd * gv.w + bv.w};
    reinterpret_cast<float4*>(out + (size_t)row * 256)[lane] = o;
}

// ---------- deformable sampling ----------
__device__ inline float samp_one(const unsigned short* __restrict__ v,
                                 int b, int st, int Wl, int Hl,
                                 int x, int y, int hc)
{
    bool valid = (x >= 0) & (x < Wl) & (y >= 0) & (y < Hl);
    int xc = min(max(x, 0), Wl - 1);
    int yc = min(max(y, 0), Hl - 1);
    size_t idx = ((size_t)(b * S_ + st + yc * Wl + xc)) * 256 + hc;
    float val = bf16_bits_to_f32(v[idx]);
    return valid ? val : 0.f;
}

// grid = B*NQ blocks, 256 threads: thread = (head h = tid>>5, channel c = tid&31)
__global__ __launch_bounds__(256) void deform_k(const float* __restrict__ rp,
                                                const float* __restrict__ offb,
                                                const float* __restrict__ awlog,
                                                const unsigned short* __restrict__ value,
                                                float* __restrict__ ca)
{
    const int tok = blockIdx.x;
    const int b = tok / NQ_;
    const int h = threadIdx.x >> 5;
    const int c = threadIdx.x & 31;
    const int hc = h * HD_ + c;

    // attention-weight softmax over 16 (L*P) logits
    const float* awp = awlog + (size_t)tok * (NH_ * L_ * P_) + h * 16;
    float w[16];
    float mx = -1e30f;
    #pragma unroll
    for (int i = 0; i < 16; i++) { w[i] = awp[i]; mx = fmaxf(mx, w[i]); }
    float sum = 0.f;
    #pragma unroll
    for (int i = 0; i < 16; i++) { w[i] = __expf(w[i] - mx); sum += w[i]; }
    const float inv = 1.f / sum;

    const float* rpp  = rp + (size_t)tok * (L_ * 4);
    const float* offp = offb + (size_t)tok * 256 + h * (L_ * P_ * 2);

    const int lvlW[4] = {128, 64, 32, 16};
    const int lvlS[4] = {0, 16384, 20480, 21504};

    float acc = 0.f;
    #pragma unroll
    for (int l = 0; l < 4; l++) {
        const int Wl = lvlW[l], Hl = lvlW[l], st = lvlS[l];
        const float cx = rpp[l * 4 + 0], cy = rpp[l * 4 + 1];
        const float cw = rpp[l * 4 + 2], chh = rpp[l * 4 + 3];
        #pragma unroll
        for (int p = 0; p < 4; p++) {
            float ox = offp[l * 8 + p * 2 + 0];
            float oy = offp[l * 8 + p * 2 + 1];
            float lx = (cx + ox * 0.25f * cw * 0.5f) * Wl - 0.5f;
            float ly = (cy + oy * 0.25f * chh * 0.5f) * Hl - 0.5f;
            float x0f = floorf(lx), y0f = floorf(ly);
            float tx = lx - x0f, ty = ly - y0f;
            int x0 = (int)x0f, y0 = (int)y0f;
            float g00 = samp_one(value, b, st, Wl, Hl, x0,     y0,     hc);
            float g01 = samp_one(value, b, st, Wl, Hl, x0 + 1, y0,     hc);
            float g10 = samp_one(value, b, st, Wl, Hl, x0,     y0 + 1, hc);
            float g11 = samp_one(value, b, st, Wl, Hl, x0 + 1, y0 + 1, hc);
            float bil = g00 * (1.f - tx) * (1.f - ty) + g01 * tx * (1.f - ty)
                      + g10 * (1.f - tx) * ty         + g11 * tx * ty;
            acc += w[l * 4 + p] * inv * bil;
        }
    }
    ca[(size_t)tok * 256 + hc] = acc;
}

// ---------- launch ----------
extern "C" void kernel_launch(void* const* d_in, const int* in_sizes, int n_in,
                              void* d_out, int out_size, void* d_ws, size_t ws_size,
                              hipStream_t stream)
{
    const float* query      = (const float*)d_in[0];
    const float* query_pos  = (const float*)d_in[1];
    const float* ref_pts    = (const float*)d_in[2];
    const float* input_flat = (const float*)d_in[3];
    const float* Wq = (const float*)d_in[6];  const float* bq = (const float*)d_in[7];
    const float* Wk = (const float*)d_in[8];  const float* bk = (const float*)d_in[9];
    const float* Wv = (const float*)d_in[10]; const float* bv = (const float*)d_in[11];
    const float* Wo = (const float*)d_in[12]; const float* bo = (const float*)d_in[13];
    const float* ln1g = (const float*)d_in[14]; const float* ln1b = (const float*)d_in[15];
    const float* W_off = (const float*)d_in[16]; const float* b_off = (const float*)d_in[17];
    const float* W_attn = (const float*)d_in[18]; const float* b_attn = (const float*)d_in[19];
    const float* W_val = (const float*)d_in[20]; const float* b_val = (const float*)d_in[21];
    const float* W_cout = (const float*)d_in[22]; const float* b_cout = (const float*)d_in[23];
    const float* ln2g = (const float*)d_in[24]; const float* ln2b = (const float*)d_in[25];
    const float* W1 = (const float*)d_in[26]; const float* b1 = (const float*)d_in[27];
    const float* W2 = (const float*)d_in[28]; const float* b2 = (const float*)d_in[29];
    const float* ln3g = (const float*)d_in[30]; const float* ln3b = (const float*)d_in[31];
    float* out = (float*)d_out;

    float* ws = (float*)d_ws;
    const size_t T = (size_t)NTOK * D_;      // 2,048,000 floats
    float* bufA = ws;
    float* bufB = bufA + T;
    float* bufC = bufB + T;
    float* bufD = bufC + T;
    float* bufE = bufD + T;                  // x (after LN1)
    float* bufF = bufE + T;                  // x2 (after LN2)
    float* bufH = bufF + T;                  // FFN hidden: 8000*1024 floats
    unsigned short* value = (unsigned short*)(bufH + (size_t)NTOK * DFF_);

    dim3 blk(256);

    // q = (query+pos) @ Wq + bq ; k = (query+pos) @ Wk + bk ; v = query @ Wv + bv
    gemm_k<true,  false, false><<<dim3(125, 4), blk, 0, stream>>>(query, query_pos, Wq, bq, bufA, nullptr, NTOK, 256, 256);
    gemm_k<true,  false, false><<<dim3(125, 4), blk, 0, stream>>>(query, query_pos, Wk, bk, bufB, nullptr, NTOK, 256, 256);
    gemm_k<false, false, false><<<dim3(125, 4), blk, 0, stream>>>(query, nullptr,   Wv, bv, bufC, nullptr, NTOK, 256, 256);
    // self-attention -> bufD
    attn_k<<<dim3(4, NH_, B_), blk, 0, stream>>>(bufA, bufB, bufC, bufD);
    // sa @ Wo + bo -> bufA ; x = LN(query + bufA) -> bufE
    gemm_k<false, false, false><<<dim3(125, 4), blk, 0, stream>>>(bufD, nullptr, Wo, bo, bufA, nullptr, NTOK, 256, 256);
    ln_k<<<NTOK / 4, blk, 0, stream>>>(query, bufA, ln1g, ln1b, bufE);
    // value = input_flatten @ W_val + b_val  (bf16 out)
    gemm_k<false, false, true><<<dim3((B_ * S_) / 64, 4), blk, 0, stream>>>(input_flat, nullptr, W_val, b_val, nullptr, value, B_ * S_, 256, 256);
    // off = (x+pos) @ W_off ; aw_logits = (x+pos) @ W_attn
    gemm_k<true,  false, false><<<dim3(125, 4), blk, 0, stream>>>(bufE, query_pos, W_off,  b_off,  bufA, nullptr, NTOK, 256, 256);
    gemm_k<true,  false, false><<<dim3(125, 2), blk, 0, stream>>>(bufE, query_pos, W_attn, b_attn, bufB, nullptr, NTOK, 128, 256);
    // deformable sampling -> bufC
    deform_k<<<NTOK, blk, 0, stream>>>(ref_pts, bufA, bufB, value, bufC);
    // ca @ W_cout + b_cout -> bufD ; x2 = LN(x + bufD) -> bufF
    gemm_k<false, false, false><<<dim3(125, 4), blk, 0, stream>>>(bufC, nullptr, W_cout, b_cout, bufD, nullptr, NTOK, 256, 256);
    ln_k<<<NTOK / 4, blk, 0, stream>>>(bufE, bufD, ln2g, ln2b, bufF);
    // FFN: h = relu(x2 @ W1 + b1) ; y = h @ W2 + b2 ; out = LN(x2 + y)
    gemm_k<false, true,  false><<<dim3(125, 16), blk, 0, stream>>>(bufF, nullptr, W1, b1, bufH, nullptr, NTOK, DFF_, 256);
    gemm_k<false, false, false><<<dim3(125, 4), blk, 0, stream>>>(bufH, nullptr, W2, b2, bufA, nullptr, NTOK, 256, DFF_);
    ln_k<<<NTOK / 4, blk, 0, stream>>>(bufF, bufA, ln3g, ln3b, out);
}

// Round 2
// 488.988 us; speedup vs baseline: 2.2166x; 2.2166x over previous
//
#include <hip/hip_runtime.h>
#include <hip/hip_bf16.h>

#define B_   8
#define NQ_  1000
#define D_   256
#define NH_  8
#define L_   4
#define P_   4
#define DFF_ 1024
#define HD_  32
#define S_   21760
#define NTOK (B_*NQ_)

typedef short  bf16x8 __attribute__((ext_vector_type(8)));
typedef float  f32x4  __attribute__((ext_vector_type(4)));

__device__ inline unsigned short f32_to_bf16_bits(float f) {
    unsigned int u = __float_as_uint(f);
    unsigned int rounding = 0x7FFFu + ((u >> 16) & 1u);
    u += rounding;
    return (unsigned short)(u >> 16);
}
__device__ inline float bf16_bits_to_f32(unsigned short b) {
    return __uint_as_float(((unsigned int)b) << 16);
}
__device__ inline void async_copy16(const void* g, void* l) {
    __builtin_amdgcn_global_load_lds((const __attribute__((address_space(1))) unsigned int*)g,
                                     (__attribute__((address_space(3))) unsigned int*)l, 16, 0, 0);
}

// ============================================================================
// MFMA GEMM: C[M,N] = A[M,K] @ Bt[N,K]^T + bias.  Tile 128x128, BK=64,
// 4 waves, each wave 64x64 (4x4 frags of 16x16x32 bf16 MFMA).
// AMODE: 0 = A is bf16 [M][K] (global_load_lds, pre-swizzled source)
//        1 = A is f32  [M][K] (reg-stage + cvt + swizzled ds_write)
//        2 = like 1 plus elementwise add of A2 (f32)
// LDS layout per operand: [128 rows][64 k] bf16, byte ^= ((row&7)<<4) swizzle.
// ============================================================================
template<int AMODE, bool RELU, bool OBF>
__global__ __launch_bounds__(256) void mgemm(const void* __restrict__ Av,
                                             const float* __restrict__ A2,
                                             const unsigned short* __restrict__ Bt,
                                             const float* __restrict__ bias,
                                             float* __restrict__ Cf,
                                             unsigned short* __restrict__ Cb,
                                             int M, int N, int K)
{
    __shared__ __align__(16) unsigned short sA[128 * 64];
    __shared__ __align__(16) unsigned short sB[128 * 64];
    const int tid = threadIdx.x;
    const int w = tid >> 6, l = tid & 63;
    const int n0 = blockIdx.x * 128, m0 = blockIdx.y * 128;
    const int wr = w >> 1, wc = w & 1;

    const unsigned short* Ab = (const unsigned short*)Av;
    const float* Af = (const float*)Av;

    f32x4 acc[4][4];
    #pragma unroll
    for (int i = 0; i < 4; i++)
        #pragma unroll
        for (int j = 0; j < 4; j++)
            #pragma unroll
            for (int r = 0; r < 4; r++) acc[i][j][r] = 0.f;

    for (int k0 = 0; k0 < K; k0 += 64) {
        __syncthreads();
        // ---- stage B (bf16 weights) via global_load_lds, pre-swizzled source ----
        #pragma unroll
        for (int r = 0; r < 4; r++) {
            int boff = ((r * 4 + w) * 64 + l) * 16;            // linear LDS byte
            int row  = boff >> 7;
            int kb   = (boff & 127) ^ ((row & 7) << 4);        // logical k-byte
            const unsigned short* gp = Bt + (size_t)(n0 + row) * K + k0 + (kb >> 1);
            async_copy16(gp, sB + (size_t)(r * 4 + w) * 512);
        }
        // ---- stage A ----
        if constexpr (AMODE == 0) {
            #pragma unroll
            for (int r = 0; r < 4; r++) {
                int boff = ((r * 4 + w) * 64 + l) * 16;
                int row  = boff >> 7;
                int kb   = (boff & 127) ^ ((row & 7) << 4);
                int grow = m0 + row; if (grow > M - 1) grow = M - 1;
                const unsigned short* gp = Ab + (size_t)grow * K + k0 + (kb >> 1);
                async_copy16(gp, sA + (size_t)(r * 4 + w) * 512);
            }
        } else {
            #pragma unroll
            for (int r = 0; r < 4; r++) {
                int g = r * 256 + tid;          // 0..1023 groups of 8 k
                int row = g >> 3;
                int ko  = (g & 7) * 8;
                int grow = m0 + row; if (grow > M - 1) grow = M - 1;
                const float* ap = Af + (size_t)grow * K + k0 + ko;
                float4 f0 = *reinterpret_cast<const float4*>(ap);
                float4 f1 = *reinterpret_cast<const float4*>(ap + 4);
                if constexpr (AMODE == 2) {
                    const float* a2 = A2 + (size_t)grow * K + k0 + ko;
                    float4 g0 = *reinterpret_cast<const float4*>(a2);
                    float4 g1 = *reinterpret_cast<const float4*>(a2 + 4);
                    f0.x += g0.x; f0.y += g0.y; f0.z += g0.z; f0.w += g0.w;
                    f1.x += g1.x; f1.y += g1.y; f1.z += g1.z; f1.w += g1.w;
                }
                bf16x8 pk;
                pk[0] = (short)f32_to_bf16_bits(f0.x); pk[1] = (short)f32_to_bf16_bits(f0.y);
                pk[2] = (short)f32_to_bf16_bits(f0.z); pk[3] = (short)f32_to_bf16_bits(f0.w);
                pk[4] = (short)f32_to_bf16_bits(f1.x); pk[5] = (short)f32_to_bf16_bits(f1.y);
                pk[6] = (short)f32_to_bf16_bits(f1.z); pk[7] = (short)f32_to_bf16_bits(f1.w);
                int sw = (ko * 2) ^ ((row & 7) << 4);
                *reinterpret_cast<bf16x8*>(&sA[row * 64 + (sw >> 1)]) = pk;
            }
        }
        __syncthreads();   // drains vmcnt (async B/A) + lgkm (A ds_write)

        // ---- compute: 2 k-halves of 32, 16 MFMA each ----
        #pragma unroll
        for (int kk = 0; kk < 2; kk++) {
            bf16x8 afr[4], bfr[4];
            const int kbyte = kk * 64 + ((l >> 4) << 4);
            #pragma unroll
            for (int mi = 0; mi < 4; mi++) {
                int row = wr * 64 + mi * 16 + (l & 15);
                int sw = kbyte ^ ((row & 7) << 4);
                afr[mi] = *reinterpret_cast<const bf16x8*>(&sA[row * 64 + (sw >> 1)]);
            }
            #pragma unroll
            for (int ni = 0; ni < 4; ni++) {
                int row = wc * 64 + ni * 16 + (l & 15);
                int sw = kbyte ^ ((row & 7) << 4);
                bfr[ni] = *reinterpret_cast<const bf16x8*>(&sB[row * 64 + (sw >> 1)]);
            }
            #pragma unroll
            for (int mi = 0; mi < 4; mi++)
                #pragma unroll
                for (int ni = 0; ni < 4; ni++)
                    acc[mi][ni] = __builtin_amdgcn_mfma_f32_16x16x32_bf16(
                        afr[mi], bfr[ni], acc[mi][ni], 0, 0, 0);
        }
    }

    // ---- epilogue ----
    #pragma unroll
    for (int mi = 0; mi < 4; mi++) {
        #pragma unroll
        for (int ni = 0; ni < 4; ni++) {
            int col = n0 + wc * 64 + ni * 16 + (l & 15);
            float bz = bias[col];
            #pragma unroll
            for (int rg = 0; rg < 4; rg++) {
                int row = m0 + wr * 64 + mi * 16 + ((l >> 4) << 2) + rg;
                if (row < M) {
                    float v = acc[mi][ni][rg] + bz;
                    if (RELU) v = fmaxf(v, 0.f);
                    if constexpr (OBF)
                        Cb[(size_t)row * N + col] = f32_to_bf16_bits(v);
                    else
                        Cf[(size_t)row * N + col] = v;
                }
            }
        }
    }
}

// ============================================================================
// Weight transpose + bf16 convert: dst[n*K+k] = bf16(src[k*N+n])
// ============================================================================
struct WJobs {
    const float* src[10];
    unsigned short* dst[10];
    int K[10], N[10];
};
__global__ __launch_bounds__(256) void wconv_k(WJobs j)
{
    int job = blockIdx.y;
    int idx = blockIdx.x * 256 + threadIdx.x;
    int K = j.K[job], N = j.N[job];
    if (idx >= K * N) return;
    int n = idx / K, k = idx - n * K;
    j.dst[job][idx] = f32_to_bf16_bits(j.src[job][(size_t)k * N + n]);
}

__global__ __launch_bounds__(1024) void biaspack_k(const float* bq, const float* bk,
                                                   const float* boff, const float* battn,
                                                   float* qkb, float* oab)
{
    int t = threadIdx.x;
    if (t < 256)      qkb[t] = bq[t];
    else if (t < 512) qkb[t] = bk[t - 256];
    else if (t < 768) oab[t - 512] = boff[t - 512];
    else if (t < 896) oab[t - 512] = battn[t - 768];
}

// ============================================================================
// Self-attention: block = 64 queries x 4 key-partitions, defer-max softmax.
// qk: [NTOK][512] f32 (q cols 0-255, k cols 256-511); v: [NTOK][256] f32.
// out: bf16 [NTOK][256].
// ============================================================================
__global__ __launch_bounds__(256) void attn2_k(const float* __restrict__ qk,
                                               const float* __restrict__ vbuf,
                                               unsigned short* __restrict__ sa)
{
    const int b = blockIdx.z, h = blockIdx.y;
    const int qbase = blockIdx.x * 64;
    const int tid = threadIdx.x;
    const int ql = tid >> 2, quarter = tid & 3;
    const int qg = qbase + ql;
    const bool qv = qg < NQ_;

    __shared__ __align__(16) float smem[9216];   // 36 KB
    float* Ks = smem;             // [128][36]
    float* Vs = smem + 128 * 36;  // [128][36]

    float qr[HD_];
    {
        const int qc = qv ? qg : (NQ_ - 1);
        const float* qrow = qk + ((size_t)(b * NQ_ + qc)) * 512 + h * HD_;
        #pragma unroll
        for (int i = 0; i < 8; i++) {
            float4 t = reinterpret_cast<const float4*>(qrow)[i];
            const float sc = 0.17677669529663687f;
            qr[4 * i + 0] = t.x * sc; qr[4 * i + 1] = t.y * sc;
            qr[4 * i + 2] = t.z * sc; qr[4 * i + 3] = t.w * sc;
        }
    }

    float m = -1e30f, s = 0.f;
    float acc[HD_];
    #pragma unroll
    for (int c = 0; c < HD_; c++) acc[c] = 0.f;

    for (int kt = 0; kt < 8; kt++) {
        __syncthreads();
        #pragma unroll
        for (int r = 0; r < 4; r++) {
            int idx = r * 256 + tid;          // 0..1023
            int krow = idx >> 3, kc4 = idx & 7;
            int gk = kt * 128 + krow;
            int gkc = gk < NQ_ ? gk : (NQ_ - 1);
            float4 kv = *reinterpret_cast<const float4*>(
                qk + ((size_t)(b * NQ_ + gkc)) * 512 + 256 + h * HD_ + kc4 * 4);
            float4 vv = *reinterpret_cast<const float4*>(
                vbuf + ((size_t)(b * NQ_ + gkc)) * 256 + h * HD_ + kc4 * 4);
            *reinterpret_cast<float4*>(Ks + krow * 36 + kc4 * 4) = kv;
            *reinterpret_cast<float4*>(Vs + krow * 36 + kc4 * 4) = vv;
        }
        __syncthreads();
        const int limit = min(128, NQ_ - kt * 128);
        for (int jj = 0; jj < 32; jj++) {
            int jl = jj * 4 + quarter;
            if (jl >= limit) break;
            const float* kr = Ks + jl * 36;
            float sc = 0.f;
            #pragma unroll
            for (int c4 = 0; c4 < 8; c4++) {
                float4 k4 = *reinterpret_cast<const float4*>(kr + c4 * 4);
                sc += qr[4 * c4] * k4.x + qr[4 * c4 + 1] * k4.y
                    + qr[4 * c4 + 2] * k4.z + qr[4 * c4 + 3] * k4.w;
            }
            if (sc > m + 8.f) {          // defer-max: almost never fires
                float corr = __expf(m - sc);
                s *= corr;
                #pragma unroll
                for (int c = 0; c < HD_; c++) acc[c] *= corr;
                m = sc;
            }
            float p = __expf(sc - m);
            s += p;
            const float* vr = Vs + jl * 36;
            #pragma unroll
            for (int c4 = 0; c4 < 8; c4++) {
                float4 v4 = *reinterpret_cast<const float4*>(vr + c4 * 4);
                acc[4 * c4 + 0] += p * v4.x; acc[4 * c4 + 1] += p * v4.y;
                acc[4 * c4 + 2] += p * v4.z; acc[4 * c4 + 3] += p * v4.w;
            }
        }
    }

    // ---- merge the 4 partials per query ----
    __syncthreads();
    float* pb = smem;                       // 64*4*36 floats = 36KB
    float* mine = pb + (ql * 4 + quarter) * 36;
    #pragma unroll
    for (int c = 0; c < HD_; c++) mine[c] = acc[c];
    mine[32] = m; mine[33] = s;
    __syncthreads();
    if (tid < 64 && (qbase + tid) < NQ_) {
        const float* p0 = pb + (tid * 4) * 36;
        float m0 = p0[32], m1 = p0[36 + 32], m2 = p0[72 + 32], m3 = p0[108 + 32];
        float M4 = fmaxf(fmaxf(m0, m1), fmaxf(m2, m3));
        float w0 = __expf(m0 - M4), w1 = __expf(m1 - M4);
        float w2 = __expf(m2 - M4), w3 = __expf(m3 - M4);
        float S = p0[33] * w0 + p0[36 + 33] * w1 + p0[72 + 33] * w2 + p0[108 + 33] * w3;
        float inv = 1.f / S;
        unsigned short* orow = sa + ((size_t)(b * NQ_ + qbase + tid)) * 256 + h * HD_;
        #pragma unroll
        for (int c = 0; c < HD_; c++) {
            float v = (p0[c] * w0 + p0[36 + c] * w1 + p0[72 + c] * w2 + p0[108 + c] * w3) * inv;
            orow[c] = f32_to_bf16_bits(v);
        }
    }
}

// ============================================================================
// LayerNorm: out = LN(a + b) * g + be, rows of 256
// ============================================================================
__global__ __launch_bounds__(256) void ln_k(const float* __restrict__ a,
                                            const float* __restrict__ bsum,
                                            const float* __restrict__ g,
                                            const float* __restrict__ be,
                                            float* __restrict__ out)
{
    const int wave = threadIdx.x >> 6, lane = threadIdx.x & 63;
    const int row = blockIdx.x * 4 + wave;
    float4 xa = reinterpret_cast<const float4*>(a + (size_t)row * 256)[lane];
    float4 xb = reinterpret_cast<const float4*>(bsum + (size_t)row * 256)[lane];
    float4 x = {xa.x + xb.x, xa.y + xb.y, xa.z + xb.z, xa.w + xb.w};
    float s  = x.x + x.y + x.z + x.w;
    float ss = x.x * x.x + x.y * x.y + x.z * x.z + x.w * x.w;
    #pragma unroll
    for (int off = 32; off > 0; off >>= 1) {
        s  += __shfl_xor(s, off);
        ss += __shfl_xor(ss, off);
    }
    float mu  = s * (1.f / 256.f);
    float var = ss * (1.f / 256.f) - mu * mu;
    float rstd = rsqrtf(var + 1e-5f);
    float4 gv = reinterpret_cast<const float4*>(g)[lane];
    float4 bv = reinterpret_cast<const float4*>(be)[lane];
    float4 o = {(x.x - mu) * rstd * gv.x + bv.x,
                (x.y - mu) * rstd * gv.y + bv.y,
                (x.z - mu) * rstd * gv.z + bv.z,
                (x.w - mu) * rstd * gv.w + bv.w};
    reinterpret_cast<float4*>(out + (size_t)row * 256)[lane] = o;
}

// ============================================================================
// Deformable sampling. oa: [NTOK][384] f32 (off cols 0-255, aw cols 256-383)
// value bf16 [B][S][256]; out ca bf16 [NTOK][256]
// ============================================================================
__device__ inline float samp_one(const unsigned short* __restrict__ v,
                                 int b, int st, int Wl, int Hl,
                                 int x, int y, int hc)
{
    bool valid = (x >= 0) & (x < Wl) & (y >= 0) & (y < Hl);
    int xc = min(max(x, 0), Wl - 1);
    int yc = min(max(y, 0), Hl - 1);
    size_t idx = ((size_t)(b * S_ + st + yc * Wl + xc)) * 256 + hc;
    float val = bf16_bits_to_f32(v[idx]);
    return valid ? val : 0.f;
}

__global__ __launch_bounds__(256) void deform_k(const float* __restrict__ rp,
                                                const float* __restrict__ oa,
                                                const unsigned short* __restrict__ value,
                                                unsigned short* __restrict__ ca)
{
    const int tok = blockIdx.x;
    const int b = tok / NQ_;
    const int h = threadIdx.x >> 5;
    const int c = threadIdx.x & 31;
    const int hc = h * HD_ + c;

    const float* awp = oa + (size_t)tok * 384 + 256 + h * 16;
    float w[16];
    float mx = -1e30f;
    #pragma unroll
    for (int i = 0; i < 16; i++) { w[i] = awp[i]; mx = fmaxf(mx, w[i]); }
    float sum = 0.f;
    #pragma unroll
    for (int i = 0; i < 16; i++) { w[i] = __expf(w[i] - mx); sum += w[i]; }
    const float inv = 1.f / sum;

    const float* rpp  = rp + (size_t)tok * (L_ * 4);
    const float* offp = oa + (size_t)tok * 384 + h * 32;

    const int lvlW[4] = {128, 64, 32, 16};
    const int lvlS[4] = {0, 16384, 20480, 21504};

    float acc = 0.f;
    #pragma unroll
    for (int l = 0; l < 4; l++) {
        const int Wl = lvlW[l], Hl = lvlW[l], st = lvlS[l];
        const float cx = rpp[l * 4 + 0], cy = rpp[l * 4 + 1];
        const float cw = rpp[l * 4 + 2], chh = rpp[l * 4 + 3];
        #pragma unroll
        for (int p = 0; p < 4; p++) {
            float ox = offp[l * 8 + p * 2 + 0];
            float oy = offp[l * 8 + p * 2 + 1];
            float lx = (cx + ox * 0.25f * cw * 0.5f) * Wl - 0.5f;
            float ly = (cy + oy * 0.25f * chh * 0.5f) * Hl - 0.5f;
            float x0f = floorf(lx), y0f = floorf(ly);
            float tx = lx - x0f, ty = ly - y0f;
            int x0 = (int)x0f, y0 = (int)y0f;
            float g00 = samp_one(value, b, st, Wl, Hl, x0,     y0,     hc);
            float g01 = samp_one(value, b, st, Wl, Hl, x0 + 1, y0,     hc);
            float g10 = samp_one(value, b, st, Wl, Hl, x0,     y0 + 1, hc);
            float g11 = samp_one(value, b, st, Wl, Hl, x0 + 1, y0 + 1, hc);
            float bil = g00 * (1.f - tx) * (1.f - ty) + g01 * tx * (1.f - ty)
                      + g10 * (1.f - tx) * ty         + g11 * tx * ty;
            acc += w[l * 4 + p] * inv * bil;
        }
    }
    ca[(size_t)tok * 256 + hc] = f32_to_bf16_bits(acc);
}

// ============================================================================
extern "C" void kernel_launch(void* const* d_in, const int* in_sizes, int n_in,
                              void* d_out, int out_size, void* d_ws, size_t ws_size,
                              hipStream_t stream)
{
    const float* query      = (const float*)d_in[0];
    const float* query_pos  = (const float*)d_in[1];
    const float* ref_pts    = (const float*)d_in[2];
    const float* input_flat = (const float*)d_in[3];
    const float* Wq = (const float*)d_in[6];  const float* bq = (const float*)d_in[7];
    const float* Wk = (const float*)d_in[8];  const float* bk = (const float*)d_in[9];
    const float* Wv = (const float*)d_in[10]; const float* bv = (const float*)d_in[11];
    const float* Wo = (const float*)d_in[12]; const float* bo = (const float*)d_in[13];
    const float* ln1g = (const float*)d_in[14]; const float* ln1b = (const float*)d_in[15];
    const float* W_off = (const float*)d_in[16]; const float* b_off = (const float*)d_in[17];
    const float* W_attn = (const float*)d_in[18]; const float* b_attn = (const float*)d_in[19];
    const float* W_val = (const float*)d_in[20]; const float* b_val = (const float*)d_in[21];
    const float* W_cout = (const float*)d_in[22]; const float* b_cout = (const float*)d_in[23];
    const float* ln2g = (const float*)d_in[24]; const float* ln2b = (const float*)d_in[25];
    const float* W1 = (const float*)d_in[26]; const float* b1 = (const float*)d_in[27];
    const float* W2 = (const float*)d_in[28]; const float* b2 = (const float*)d_in[29];
    const float* ln3g = (const float*)d_in[30]; const float* ln3b = (const float*)d_in[31];
    float* out = (float*)d_out;

    // ---- workspace arena ----
    char* base = (char*)d_ws;
    size_t off = 0;
    auto alloc = [&](size_t bytes) { void* p = base + off; off += (bytes + 255) & ~(size_t)255; return p; };
    unsigned short* value_bf = (unsigned short*)alloc((size_t)B_ * S_ * 256 * 2);   // 89.1 MB
    float* qk_buf = (float*)alloc((size_t)NTOK * 512 * 4);                          // 16.4 MB (∪ h_bf)
    unsigned short* h_bf = (unsigned short*)qk_buf;                                 // [NTOK][1024] bf16
    float* big2   = (float*)alloc((size_t)NTOK * 384 * 4);                          // v_buf ∪ oa_buf
    float* v_buf  = big2;
    float* oa_buf = big2;
    float* tmp0   = (float*)alloc((size_t)NTOK * 256 * 4);
    float* x1     = (float*)alloc((size_t)NTOK * 256 * 4);
    float* x2     = (float*)alloc((size_t)NTOK * 256 * 4);
    unsigned short* sc_bf = (unsigned short*)alloc((size_t)NTOK * 256 * 2);         // sa ∪ ca
    unsigned short* wqk   = (unsigned short*)alloc(512 * 256 * 2);
    unsigned short* wv    = (unsigned short*)alloc(256 * 256 * 2);
    unsigned short* wo    = (unsigned short*)alloc(256 * 256 * 2);
    unsigned short* woa   = (unsigned short*)alloc(384 * 256 * 2);
    unsigned short* wval  = (unsigned short*)alloc(256 * 256 * 2);
    unsigned short* wcout = (unsigned short*)alloc(256 * 256 * 2);
    unsigned short* w1t   = (unsigned short*)alloc(1024 * 256 * 2);
    unsigned short* w2t   = (unsigned short*)alloc(256 * 1024 * 2);
    float* qkbias = (float*)alloc(512 * 4);
    float* oabias = (float*)alloc(384 * 4);

    dim3 blk(256);

    // ---- weight prep ----
    WJobs wj;
    wj.src[0] = Wq;    wj.dst[0] = wqk;               wj.K[0] = 256;  wj.N[0] = 256;
    wj.src[1] = Wk;    wj.dst[1] = wqk + 256 * 256;   wj.K[1] = 256;  wj.N[1] = 256;
    wj.src[2] = Wv;    wj.dst[2] = wv;                wj.K[2] = 256;  wj.N[2] = 256;
    wj.src[3] = Wo;    wj.dst[3] = wo;                wj.K[3] = 256;  wj.N[3] = 256;
    wj.src[4] = W_off; wj.dst[4] = woa;               wj.K[4] = 256;  wj.N[4] = 256;
    wj.src[5] = W_attn;wj.dst[5] = woa + 256 * 256;   wj.K[5] = 256;  wj.N[5] = 128;
    wj.src[6] = W_val; wj.dst[6] = wval;              wj.K[6] = 256;  wj.N[6] = 256;
    wj.src[7] = W_cout;wj.dst[7] = wcout;             wj.K[7] = 256;  wj.N[7] = 256;
    wj.src[8] = W1;    wj.dst[8] = w1t;               wj.K[8] = 256;  wj.N[8] = 1024;
    wj.src[9] = W2;    wj.dst[9] = w2t;               wj.K[9] = 1024; wj.N[9] = 256;
    wconv_k<<<dim3(1024, 10), blk, 0, stream>>>(wj);
    biaspack_k<<<1, 1024, 0, stream>>>(bq, bk, b_off, b_attn, qkbias, oabias);

    // ---- self-attention block ----
    mgemm<2, false, false><<<dim3(4, 63), blk, 0, stream>>>(query, query_pos, wqk, qkbias, qk_buf, nullptr, NTOK, 512, 256);
    mgemm<1, false, false><<<dim3(2, 63), blk, 0, stream>>>(query, nullptr,   wv,  bv,     v_buf,  nullptr, NTOK, 256, 256);
    attn2_k<<<dim3(16, NH_, B_), blk, 0, stream>>>(qk_buf, v_buf, sc_bf);
    mgemm<0, false, false><<<dim3(2, 63), blk, 0, stream>>>(sc_bf, nullptr, wo, bo, tmp0, nullptr, NTOK, 256, 256);
    ln_k<<<NTOK / 4, blk, 0, stream>>>(query, tmp0, ln1g, ln1b, x1);

    // ---- deformable cross-attention ----
    mgemm<1, false, true ><<<dim3(2, 1360), blk, 0, stream>>>(input_flat, nullptr, wval, b_val, nullptr, value_bf, B_ * S_, 256, 256);
    mgemm<2, false, false><<<dim3(3, 63),  blk, 0, stream>>>(x1, query_pos, woa, oabias, oa_buf, nullptr, NTOK, 384, 256);
    deform_k<<<NTOK, blk, 0, stream>>>(ref_pts, oa_buf, value_bf, sc_bf);
    mgemm<0, false, false><<<dim3(2, 63), blk, 0, stream>>>(sc_bf, nullptr, wcout, b_cout, tmp0, nullptr, NTOK, 256, 256);
    ln_k<<<NTOK / 4, blk, 0, stream>>>(x1, tmp0, ln2g, ln2b, x2);

    // ---- FFN ----
    mgemm<1, true,  true ><<<dim3(8, 63), blk, 0, stream>>>(x2, nullptr, w1t, b1, nullptr, h_bf, NTOK, DFF_, 256);
    mgemm<0, false, false><<<dim3(2, 63), blk, 0, stream>>>(h_bf, nullptr, w2t, b2, tmp0, nullptr, NTOK, 256, DFF_);
    ln_k<<<NTOK / 4, blk, 0, stream>>>(x2, tmp0, ln3g, ln3b, out);
}

// Round 3
// 367.008 us; speedup vs baseline: 2.9534x; 1.3324x over previous
//
#include <hip/hip_runtime.h>
#include <hip/hip_bf16.h>

#define B_   8
#define NQ_  1000
#define D_   256
#define NH_  8
#define L_   4
#define P_   4
#define DFF_ 1024
#define HD_  32
#define S_   21760
#define NTOK (B_*NQ_)

typedef short  bf16x8 __attribute__((ext_vector_type(8)));
typedef float  f32x4  __attribute__((ext_vector_type(4)));

__device__ inline unsigned short f32_to_bf16_bits(float f) {
    unsigned int u = __float_as_uint(f);
    unsigned int rounding = 0x7FFFu + ((u >> 16) & 1u);
    u += rounding;
    return (unsigned short)(u >> 16);
}
__device__ inline float bf16_bits_to_f32(unsigned short b) {
    return __uint_as_float(((unsigned int)b) << 16);
}
__device__ inline void async_copy16(const void* g, void* l) {
    __builtin_amdgcn_global_load_lds((const __attribute__((address_space(1))) unsigned int*)g,
                                     (__attribute__((address_space(3))) unsigned int*)l, 16, 0, 0);
}

// ============================================================================
// MFMA GEMM: C[M,N] = A[M,K] @ Bt[N,K]^T + bias.  Tile 128x128, BK=64,
// 4 waves, each wave 64x64 (4x4 frags of 16x16x32 bf16 MFMA).
// AMODE: 0 = A bf16 [M][K]; 1 = A f32; 2 = A f32 + A2 f32 elementwise add.
// CMODE: 0 = f32 row-major; 1 = bf16 row-major;
//        2 = bf16 transposed "vt" layout [b][col][1024] (keys padded), M tokens.
// ============================================================================
template<int AMODE, bool RELU, int CMODE>
__global__ __launch_bounds__(256) void mgemm(const void* __restrict__ Av,
                                             const float* __restrict__ A2,
                                             const unsigned short* __restrict__ Bt,
                                             const float* __restrict__ bias,
                                             float* __restrict__ Cf,
                                             unsigned short* __restrict__ Cb,
                                             int M, int N, int K)
{
    __shared__ __align__(16) unsigned short sA[128 * 64];
    __shared__ __align__(16) unsigned short sB[128 * 64];
    const int tid = threadIdx.x;
    const int w = tid >> 6, l = tid & 63;
    const int n0 = blockIdx.x * 128, m0 = blockIdx.y * 128;
    const int wr = w >> 1, wc = w & 1;

    const unsigned short* Ab = (const unsigned short*)Av;
    const float* Af = (const float*)Av;

    f32x4 acc[4][4];
    #pragma unroll
    for (int i = 0; i < 4; i++)
        #pragma unroll
        for (int j = 0; j < 4; j++)
            #pragma unroll
            for (int r = 0; r < 4; r++) acc[i][j][r] = 0.f;

    for (int k0 = 0; k0 < K; k0 += 64) {
        __syncthreads();
        #pragma unroll
        for (int r = 0; r < 4; r++) {
            int boff = ((r * 4 + w) * 64 + l) * 16;
            int row  = boff >> 7;
            int kb   = (boff & 127) ^ ((row & 7) << 4);
            const unsigned short* gp = Bt + (size_t)(n0 + row) * K + k0 + (kb >> 1);
            async_copy16(gp, sB + (size_t)(r * 4 + w) * 512);
        }
        if constexpr (AMODE == 0) {
            #pragma unroll
            for (int r = 0; r < 4; r++) {
                int boff = ((r * 4 + w) * 64 + l) * 16;
                int row  = boff >> 7;
                int kb   = (boff & 127) ^ ((row & 7) << 4);
                int grow = m0 + row; if (grow > M - 1) grow = M - 1;
                const unsigned short* gp = Ab + (size_t)grow * K + k0 + (kb >> 1);
                async_copy16(gp, sA + (size_t)(r * 4 + w) * 512);
            }
        } else {
            #pragma unroll
            for (int r = 0; r < 4; r++) {
                int g = r * 256 + tid;
                int row = g >> 3;
                int ko  = (g & 7) * 8;
                int grow = m0 + row; if (grow > M - 1) grow = M - 1;
                const float* ap = Af + (size_t)grow * K + k0 + ko;
                float4 f0 = *reinterpret_cast<const float4*>(ap);
                float4 f1 = *reinterpret_cast<const float4*>(ap + 4);
                if constexpr (AMODE == 2) {
                    const float* a2 = A2 + (size_t)grow * K + k0 + ko;
                    float4 g0 = *reinterpret_cast<const float4*>(a2);
                    float4 g1 = *reinterpret_cast<const float4*>(a2 + 4);
                    f0.x += g0.x; f0.y += g0.y; f0.z += g0.z; f0.w += g0.w;
                    f1.x += g1.x; f1.y += g1.y; f1.z += g1.z; f1.w += g1.w;
                }
                bf16x8 pk;
                pk[0] = (short)f32_to_bf16_bits(f0.x); pk[1] = (short)f32_to_bf16_bits(f0.y);
                pk[2] = (short)f32_to_bf16_bits(f0.z); pk[3] = (short)f32_to_bf16_bits(f0.w);
                pk[4] = (short)f32_to_bf16_bits(f1.x); pk[5] = (short)f32_to_bf16_bits(f1.y);
                pk[6] = (short)f32_to_bf16_bits(f1.z); pk[7] = (short)f32_to_bf16_bits(f1.w);
                int sw = (ko * 2) ^ ((row & 7) << 4);
                *reinterpret_cast<bf16x8*>(&sA[row * 64 + (sw >> 1)]) = pk;
            }
        }
        __syncthreads();

        #pragma unroll
        for (int kk = 0; kk < 2; kk++) {
            bf16x8 afr[4], bfr[4];
            const int kbyte = kk * 64 + ((l >> 4) << 4);
            #pragma unroll
            for (int mi = 0; mi < 4; mi++) {
                int row = wr * 64 + mi * 16 + (l & 15);
                int sw = kbyte ^ ((row & 7) << 4);
                afr[mi] = *reinterpret_cast<const bf16x8*>(&sA[row * 64 + (sw >> 1)]);
            }
            #pragma unroll
            for (int ni = 0; ni < 4; ni++) {
                int row = wc * 64 + ni * 16 + (l & 15);
                int sw = kbyte ^ ((row & 7) << 4);
                bfr[ni] = *reinterpret_cast<const bf16x8*>(&sB[row * 64 + (sw >> 1)]);
            }
            #pragma unroll
            for (int mi = 0; mi < 4; mi++)
                #pragma unroll
                for (int ni = 0; ni < 4; ni++)
                    acc[mi][ni] = __builtin_amdgcn_mfma_f32_16x16x32_bf16(
                        afr[mi], bfr[ni], acc[mi][ni], 0, 0, 0);
        }
    }

    #pragma unroll
    for (int mi = 0; mi < 4; mi++) {
        #pragma unroll
        for (int ni = 0; ni < 4; ni++) {
            int col = n0 + wc * 64 + ni * 16 + (l & 15);
            float bz = bias[col];
            if constexpr (CMODE == 2) {
                int row0 = m0 + wr * 64 + mi * 16 + ((l >> 4) << 2);
                if (row0 + 3 < M) {
                    int bb = row0 / 1000;
                    int key = row0 - bb * 1000;
                    ushort4 q4;
                    q4.x = f32_to_bf16_bits(acc[mi][ni][0] + bz);
                    q4.y = f32_to_bf16_bits(acc[mi][ni][1] + bz);
                    q4.z = f32_to_bf16_bits(acc[mi][ni][2] + bz);
                    q4.w = f32_to_bf16_bits(acc[mi][ni][3] + bz);
                    *reinterpret_cast<ushort4*>(Cb + (size_t)bb * 262144 + (size_t)col * 1024 + key) = q4;
                }
            } else {
                #pragma unroll
                for (int rg = 0; rg < 4; rg++) {
                    int row = m0 + wr * 64 + mi * 16 + ((l >> 4) << 2) + rg;
                    if (row < M) {
                        float v = acc[mi][ni][rg] + bz;
                        if (RELU) v = fmaxf(v, 0.f);
                        if constexpr (CMODE == 1)
                            Cb[(size_t)row * N + col] = f32_to_bf16_bits(v);
                        else
                            Cf[(size_t)row * N + col] = v;
                    }
                }
            }
        }
    }
}

// ============================================================================
// Weight transpose + bf16 convert
// ============================================================================
struct WJobs {
    const float* src[10];
    unsigned short* dst[10];
    int K[10], N[10];
};
__global__ __launch_bounds__(256) void wconv_k(WJobs j)
{
    int job = blockIdx.y;
    int idx = blockIdx.x * 256 + threadIdx.x;
    int K = j.K[job], N = j.N[job];
    if (idx >= K * N) return;
    int n = idx / K, k = idx - n * K;
    j.dst[job][idx] = f32_to_bf16_bits(j.src[job][(size_t)k * N + n]);
}

__global__ __launch_bounds__(1024) void biaspack_k(const float* bq, const float* bk,
                                                   const float* boff, const float* battn,
                                                   float* qkb, float* oab)
{
    int t = threadIdx.x;
    if (t < 256)      qkb[t] = bq[t];
    else if (t < 512) qkb[t] = bk[t - 256];
    else if (t < 768) oab[t - 512] = boff[t - 512];
    else if (t < 896) oab[t - 512] = battn[t - 768];
}

// ============================================================================
// MFMA flash self-attention.
// qk: bf16 [NTOK][512] (q cols 0-255, k cols 256-511); vt: bf16 [B][256][1024].
// Block = 4 waves x 16 q-rows; grid (16, NH, B). Swapped S^T = mfma(K, Q).
// ============================================================================
__global__ __launch_bounds__(256) void fattn_k(const unsigned short* __restrict__ qk,
                                               const unsigned short* __restrict__ vt,
                                               unsigned short* __restrict__ sa)
{
    const int b = blockIdx.z, h = blockIdx.y;
    const int tid = threadIdx.x;
    const int w = tid >> 6, l = tid & 63;
    const int lq = l & 15, g = l >> 4;
    const int q0 = blockIdx.x * 64 + w * 16;

    __shared__ __align__(16) unsigned short Ks[128 * 32];   // [key][d] swz
    __shared__ __align__(16) unsigned short Vs[32 * 128];   // [d][key] swz
    __shared__ __align__(16) unsigned short Ps[4][16 * 128]; // per-wave [q][key] swz

    int qrow = q0 + lq; if (qrow > NQ_ - 1) qrow = NQ_ - 1;
    const bf16x8 qfrag = *reinterpret_cast<const bf16x8*>(
        qk + ((size_t)(b * NQ_ + qrow)) * 512 + h * 32 + g * 8);

    f32x4 O0 = {0.f, 0.f, 0.f, 0.f}, O1 = {0.f, 0.f, 0.f, 0.f};
    float m = -1e30f, lsum = 0.f;
    const float scale = 0.17677669529663687f;

    const size_t kbase = (size_t)b * (NQ_ * 512) + 256 + h * 32;
    const size_t vbase = (size_t)b * 262144 + (size_t)(h * 32) * 1024;
    const int swz = (lq & 7) << 4;

    for (int kt = 0; kt < 8; kt++) {
        const int k0 = kt * 128;
        __syncthreads();
        #pragma unroll
        for (int r = 0; r < 2; r++) {
            int lin = (r * 256 + tid) * 16;            // K tile: 8KB
            int krow = lin >> 6;
            int kb = (lin & 63) ^ ((krow & 7) << 4);
            async_copy16(qk + kbase + (size_t)(k0 + krow) * 512 + (kb >> 1),
                         (char*)Ks + lin);
            int d = lin >> 8;                          // V tile: 8KB
            int vb = (lin & 255) ^ ((d & 7) << 4);
            async_copy16(vt + vbase + (size_t)d * 1024 + k0 + (vb >> 1),
                         (char*)Vs + lin);
        }
        __syncthreads();

        // ---- S^T = K @ Q^T : one MFMA per 16-key group ----
        float t[8][4];
        float tmax = -1e30f;
        const bool tail = (k0 + 128 > NQ_);
        #pragma unroll
        for (int ni = 0; ni < 8; ni++) {
            int row = ni * 16 + lq;
            bf16x8 kf = *reinterpret_cast<const bf16x8*>(
                (char*)Ks + row * 64 + ((g * 16) ^ swz));
            f32x4 st = __builtin_amdgcn_mfma_f32_16x16x32_bf16(
                kf, qfrag, (f32x4){0.f, 0.f, 0.f, 0.f}, 0, 0, 0);
            #pragma unroll
            for (int rg = 0; rg < 4; rg++) {
                float tv = st[rg] * scale;
                if (tail) {
                    int key = k0 + ni * 16 + g * 4 + rg;
                    tv = (key < NQ_) ? tv : -1e30f;
                }
                t[ni][rg] = tv;
                tmax = fmaxf(tmax, tv);
            }
        }
        tmax = fmaxf(tmax, __shfl_xor(tmax, 16));
        tmax = fmaxf(tmax, __shfl_xor(tmax, 32));
        float mnew = fmaxf(m, tmax);
        float corr = __expf(m - mnew);
        m = mnew;

        float rs = 0.f;
        unsigned int pk[8][2];
        #pragma unroll
        for (int ni = 0; ni < 8; ni++) {
            float p0 = __expf(t[ni][0] - mnew);
            float p1 = __expf(t[ni][1] - mnew);
            float p2 = __expf(t[ni][2] - mnew);
            float p3 = __expf(t[ni][3] - mnew);
            rs += (p0 + p1) + (p2 + p3);
            pk[ni][0] = ((unsigned)f32_to_bf16_bits(p0)) | (((unsigned)f32_to_bf16_bits(p1)) << 16);
            pk[ni][1] = ((unsigned)f32_to_bf16_bits(p2)) | (((unsigned)f32_to_bf16_bits(p3)) << 16);
        }
        rs += __shfl_xor(rs, 16);
        rs += __shfl_xor(rs, 32);
        lsum = lsum * corr + rs;

        float c0 = __shfl(corr, g * 4 + 0);
        float c1 = __shfl(corr, g * 4 + 1);
        float c2 = __shfl(corr, g * 4 + 2);
        float c3 = __shfl(corr, g * 4 + 3);
        O0[0] *= c0; O0[1] *= c1; O0[2] *= c2; O0[3] *= c3;
        O1[0] *= c0; O1[1] *= c1; O1[2] *= c2; O1[3] *= c3;

        // ---- P^T -> per-wave LDS in A-frag layout ----
        unsigned short* Pw = Ps[w];
        #pragma unroll
        for (int ni = 0; ni < 8; ni++) {
            int byteoff = lq * 256 + ((ni * 32 + g * 8) ^ swz);
            *reinterpret_cast<uint2*>((char*)Pw + byteoff) = make_uint2(pk[ni][0], pk[ni][1]);
        }

        // ---- O += P @ V ----
        #pragma unroll
        for (int c = 0; c < 4; c++) {
            int rb = (c * 64 + g * 16) ^ swz;
            bf16x8 pa = *reinterpret_cast<const bf16x8*>((char*)Pw + lq * 256 + rb);
            bf16x8 v0 = *reinterpret_cast<const bf16x8*>((char*)Vs + lq * 256 + rb);
            bf16x8 v1 = *reinterpret_cast<const bf16x8*>((char*)Vs + (16 + lq) * 256 + rb);
            O0 = __builtin_amdgcn_mfma_f32_16x16x32_bf16(pa, v0, O0, 0, 0, 0);
            O1 = __builtin_amdgcn_mfma_f32_16x16x32_bf16(pa, v1, O1, 0, 0, 0);
        }
    }

    float linv = 1.f / lsum;
    float i0 = __shfl(linv, g * 4 + 0);
    float i1 = __shfl(linv, g * 4 + 1);
    float i2 = __shfl(linv, g * 4 + 2);
    float i3 = __shfl(linv, g * 4 + 3);
    float iv[4] = {i0, i1, i2, i3};
    #pragma unroll
    for (int rg = 0; rg < 4; rg++) {
        int qg = q0 + g * 4 + rg;
        if (qg < NQ_) {
            size_t obase = ((size_t)(b * NQ_ + qg)) * 256 + h * 32;
            sa[obase + lq]      = f32_to_bf16_bits(O0[rg] * iv[rg]);
            sa[obase + 16 + lq] = f32_to_bf16_bits(O1[rg] * iv[rg]);
        }
    }
}

// ============================================================================
// LayerNorm: out = LN(a + b) * g + be, rows of 256
// ============================================================================
__global__ __launch_bounds__(256) void ln_k(const float* __restrict__ a,
                                            const float* __restrict__ bsum,
                                            const float* __restrict__ g,
                                            const float* __restrict__ be,
                                            float* __restrict__ out)
{
    const int wave = threadIdx.x >> 6, lane = threadIdx.x & 63;
    const int row = blockIdx.x * 4 + wave;
    float4 xa = reinterpret_cast<const float4*>(a + (size_t)row * 256)[lane];
    float4 xb = reinterpret_cast<const float4*>(bsum + (size_t)row * 256)[lane];
    float4 x = {xa.x + xb.x, xa.y + xb.y, xa.z + xb.z, xa.w + xb.w};
    float s  = x.x + x.y + x.z + x.w;
    float ss = x.x * x.x + x.y * x.y + x.z * x.z + x.w * x.w;
    #pragma unroll
    for (int off = 32; off > 0; off >>= 1) {
        s  += __shfl_xor(s, off);
        ss += __shfl_xor(ss, off);
    }
    float mu  = s * (1.f / 256.f);
    float var = ss * (1.f / 256.f) - mu * mu;
    float rstd = rsqrtf(var + 1e-5f);
    float4 gv = reinterpret_cast<const float4*>(g)[lane];
    float4 bv = reinterpret_cast<const float4*>(be)[lane];
    float4 o = {(x.x - mu) * rstd * gv.x + bv.x,
                (x.y - mu) * rstd * gv.y + bv.y,
                (x.z - mu) * rstd * gv.z + bv.z,
                (x.w - mu) * rstd * gv.w + bv.w};
    reinterpret_cast<float4*>(out + (size_t)row * 256)[lane] = o;
}

// ============================================================================
// Deformable sampling
// ============================================================================
__device__ inline float samp_one(const unsigned short* __restrict__ v,
                                 int b, int st, int Wl, int Hl,
                                 int x, int y, int hc)
{
    bool valid = (x >= 0) & (x < Wl) & (y >= 0) & (y < Hl);
    int xc = min(max(x, 0), Wl - 1);
    int yc = min(max(y, 0), Hl - 1);
    size_t idx = ((size_t)(b * S_ + st + yc * Wl + xc)) * 256 + hc;
    float val = bf16_bits_to_f32(v[idx]);
    return valid ? val : 0.f;
}

__global__ __launch_bounds__(256) void deform_k(const float* __restrict__ rp,
                                                const float* __restrict__ oa,
                                                const unsigned short* __restrict__ value,
                                                unsigned short* __restrict__ ca)
{
    const int tok = blockIdx.x;
    const int b = tok / NQ_;
    const int h = threadIdx.x >> 5;
    const int c = threadIdx.x & 31;
    const int hc = h * HD_ + c;

    const float* awp = oa + (size_t)tok * 384 + 256 + h * 16;
    float w[16];
    float mx = -1e30f;
    #pragma unroll
    for (int i = 0; i < 16; i++) { w[i] = awp[i]; mx = fmaxf(mx, w[i]); }
    float sum = 0.f;
    #pragma unroll
    for (int i = 0; i < 16; i++) { w[i] = __expf(w[i] - mx); sum += w[i]; }
    const float inv = 1.f / sum;

    const float* rpp  = rp + (size_t)tok * (L_ * 4);
    const float* offp = oa + (size_t)tok * 384 + h * 32;

    const int lvlW[4] = {128, 64, 32, 16};
    const int lvlS[4] = {0, 16384, 20480, 21504};

    float acc = 0.f;
    #pragma unroll
    for (int l = 0; l < 4; l++) {
        const int Wl = lvlW[l], Hl = lvlW[l], st = lvlS[l];
        const float cx = rpp[l * 4 + 0], cy = rpp[l * 4 + 1];
        const float cw = rpp[l * 4 + 2], chh = rpp[l * 4 + 3];
        #pragma unroll
        for (int p = 0; p < 4; p++) {
            float ox = offp[l * 8 + p * 2 + 0];
            float oy = offp[l * 8 + p * 2 + 1];
            float lx = (cx + ox * 0.25f * cw * 0.5f) * Wl - 0.5f;
            float ly = (cy + oy * 0.25f * chh * 0.5f) * Hl - 0.5f;
            float x0f = floorf(lx), y0f = floorf(ly);
            float tx = lx - x0f, ty = ly - y0f;
            int x0 = (int)x0f, y0 = (int)y0f;
            float g00 = samp_one(value, b, st, Wl, Hl, x0,     y0,     hc);
            float g01 = samp_one(value, b, st, Wl, Hl, x0 + 1, y0,     hc);
            float g10 = samp_one(value, b, st, Wl, Hl, x0,     y0 + 1, hc);
            float g11 = samp_one(value, b, st, Wl, Hl, x0 + 1, y0 + 1, hc);
            float bil = g00 * (1.f - tx) * (1.f - ty) + g01 * tx * (1.f - ty)
                      + g10 * (1.f - tx) * ty         + g11 * tx * ty;
            acc += w[l * 4 + p] * inv * bil;
        }
    }
    ca[(size_t)tok * 256 + hc] = f32_to_bf16_bits(acc);
}

// ============================================================================
extern "C" void kernel_launch(void* const* d_in, const int* in_sizes, int n_in,
                              void* d_out, int out_size, void* d_ws, size_t ws_size,
                              hipStream_t stream)
{
    const float* query      = (const float*)d_in[0];
    const float* query_pos  = (const float*)d_in[1];
    const float* ref_pts    = (const float*)d_in[2];
    const float* input_flat = (const float*)d_in[3];
    const float* Wq = (const float*)d_in[6];  const float* bq = (const float*)d_in[7];
    const float* Wk = (const float*)d_in[8];  const float* bk = (const float*)d_in[9];
    const float* Wv = (const float*)d_in[10]; const float* bv = (const float*)d_in[11];
    const float* Wo = (const float*)d_in[12]; const float* bo = (const float*)d_in[13];
    const float* ln1g = (const float*)d_in[14]; const float* ln1b = (const float*)d_in[15];
    const float* W_off = (const float*)d_in[16]; const float* b_off = (const float*)d_in[17];
    const float* W_attn = (const float*)d_in[18]; const float* b_attn = (const float*)d_in[19];
    const float* W_val = (const float*)d_in[20]; const float* b_val = (const float*)d_in[21];
    const float* W_cout = (const float*)d_in[22]; const float* b_cout = (const float*)d_in[23];
    const float* ln2g = (const float*)d_in[24]; const float* ln2b = (const float*)d_in[25];
    const float* W1 = (const float*)d_in[26]; const float* b1 = (const float*)d_in[27];
    const float* W2 = (const float*)d_in[28]; const float* b2 = (const float*)d_in[29];
    const float* ln3g = (const float*)d_in[30]; const float* ln3b = (const float*)d_in[31];
    float* out = (float*)d_out;

    // ---- workspace arena ----
    char* base = (char*)d_ws;
    size_t off = 0;
    auto alloc = [&](size_t bytes) { void* p = base + off; off += (bytes + 255) & ~(size_t)255; return p; };
    unsigned short* value_bf = (unsigned short*)alloc((size_t)B_ * S_ * 256 * 2);   // 89.1 MB
    unsigned short* qk_bf = (unsigned short*)alloc((size_t)NTOK * 1024 * 2);        // qk [NTOK][512] ∪ h_bf [NTOK][1024]
    unsigned short* h_bf = qk_bf;
    unsigned short* vt = (unsigned short*)alloc((size_t)B_ * 256 * 1024 * 2);       // 4.2 MB
    float* oa_buf = (float*)alloc((size_t)NTOK * 384 * 4);
    float* tmp0   = (float*)alloc((size_t)NTOK * 256 * 4);
    float* x1     = (float*)alloc((size_t)NTOK * 256 * 4);
    float* x2     = (float*)alloc((size_t)NTOK * 256 * 4);
    unsigned short* sc_bf = (unsigned short*)alloc((size_t)NTOK * 256 * 2);
    unsigned short* wqk   = (unsigned short*)alloc(512 * 256 * 2);
    unsigned short* wv    = (unsigned short*)alloc(256 * 256 * 2);
    unsigned short* wo    = (unsigned short*)alloc(256 * 256 * 2);
    unsigned short* woa   = (unsigned short*)alloc(384 * 256 * 2);
    unsigned short* wval  = (unsigned short*)alloc(256 * 256 * 2);
    unsigned short* wcout = (unsigned short*)alloc(256 * 256 * 2);
    unsigned short* w1t   = (unsigned short*)alloc(1024 * 256 * 2);
    unsigned short* w2t   = (unsigned short*)alloc(256 * 1024 * 2);
    float* qkbias = (float*)alloc(512 * 4);
    float* oabias = (float*)alloc(384 * 4);

    dim3 blk(256);

    // ---- weight prep ----
    WJobs wj;
    wj.src[0] = Wq;    wj.dst[0] = wqk;               wj.K[0] = 256;  wj.N[0] = 256;
    wj.src[1] = Wk;    wj.dst[1] = wqk + 256 * 256;   wj.K[1] = 256;  wj.N[1] = 256;
    wj.src[2] = Wv;    wj.dst[2] = wv;                wj.K[2] = 256;  wj.N[2] = 256;
    wj.src[3] = Wo;    wj.dst[3] = wo;                wj.K[3] = 256;  wj.N[3] = 256;
    wj.src[4] = W_off; wj.dst[4] = woa;               wj.K[4] = 256;  wj.N[4] = 256;
    wj.src[5] = W_attn;wj.dst[5] = woa + 256 * 256;   wj.K[5] = 256;  wj.N[5] = 128;
    wj.src[6] = W_val; wj.dst[6] = wval;              wj.K[6] = 256;  wj.N[6] = 256;
    wj.src[7] = W_cout;wj.dst[7] = wcout;             wj.K[7] = 256;  wj.N[7] = 256;
    wj.src[8] = W1;    wj.dst[8] = w1t;               wj.K[8] = 256;  wj.N[8] = 1024;
    wj.src[9] = W2;    wj.dst[9] = w2t;               wj.K[9] = 1024; wj.N[9] = 256;
    wconv_k<<<dim3(1024, 10), blk, 0, stream>>>(wj);
    biaspack_k<<<1, 1024, 0, stream>>>(bq, bk, b_off, b_attn, qkbias, oabias);

    // ---- self-attention block ----
    mgemm<2, false, 1><<<dim3(4, 63), blk, 0, stream>>>(query, query_pos, wqk, qkbias, nullptr, qk_bf, NTOK, 512, 256);
    mgemm<1, false, 2><<<dim3(2, 63), blk, 0, stream>>>(query, nullptr,   wv,  bv,     nullptr, vt,    NTOK, 256, 256);
    fattn_k<<<dim3(16, NH_, B_), blk, 0, stream>>>(qk_bf, vt, sc_bf);
    mgemm<0, false, 0><<<dim3(2, 63), blk, 0, stream>>>(sc_bf, nullptr, wo, bo, tmp0, nullptr, NTOK, 256, 256);
    ln_k<<<NTOK / 4, blk, 0, stream>>>(query, tmp0, ln1g, ln1b, x1);

    // ---- deformable cross-attention ----
    mgemm<1, false, 1><<<dim3(2, 1360), blk, 0, stream>>>(input_flat, nullptr, wval, b_val, nullptr, value_bf, B_ * S_, 256, 256);
    mgemm<2, false, 0><<<dim3(3, 63),  blk, 0, stream>>>(x1, query_pos, woa, oabias, oa_buf, nullptr, NTOK, 384, 256);
    deform_k<<<NTOK, blk, 0, stream>>>(ref_pts, oa_buf, value_bf, sc_bf);
    mgemm<0, false, 0><<<dim3(2, 63), blk, 0, stream>>>(sc_bf, nullptr, wcout, b_cout, tmp0, nullptr, NTOK, 256, 256);
    ln_k<<<NTOK / 4, blk, 0, stream>>>(x1, tmp0, ln2g, ln2b, x2);

    // ---- FFN ----
    mgemm<1, true,  1><<<dim3(8, 63), blk, 0, stream>>>(x2, nullptr, w1t, b1, nullptr, h_bf, NTOK, DFF_, 256);
    mgemm<0, false, 0><<<dim3(2, 63), blk, 0, stream>>>(h_bf, nullptr, w2t, b2, tmp0, nullptr, NTOK, 256, DFF_);
    ln_k<<<NTOK / 4, blk, 0, stream>>>(x2, tmp0, ln3g, ln3b, out);
}

// Round 4
// 346.499 us; speedup vs baseline: 3.1282x; 1.0592x over previous
//
#include <hip/hip_runtime.h>
#include <hip/hip_bf16.h>

#define B_   8
#define NQ_  1000
#define D_   256
#define NH_  8
#define L_   4
#define P_   4
#define DFF_ 1024
#define HD_  32
#define S_   21760
#define NTOK (B_*NQ_)

typedef short  bf16x8 __attribute__((ext_vector_type(8)));
typedef float  f32x4  __attribute__((ext_vector_type(4)));

#define WAITBAR(N) asm volatile("s_waitcnt vmcnt(" #N ") lgkmcnt(0)\n\ts_barrier" ::: "memory")
#define ENDBAR()   asm volatile("s_barrier" ::: "memory")

__device__ inline unsigned short f32_to_bf16_bits(float f) {
    unsigned int u = __float_as_uint(f);
    unsigned int rounding = 0x7FFFu + ((u >> 16) & 1u);
    u += rounding;
    return (unsigned short)(u >> 16);
}
__device__ inline float bf16_bits_to_f32(unsigned short b) {
    return __uint_as_float(((unsigned int)b) << 16);
}
__device__ inline void async_copy16(const void* g, void* l) {
    __builtin_amdgcn_global_load_lds((const __attribute__((address_space(1))) unsigned int*)g,
                                     (__attribute__((address_space(3))) unsigned int*)l, 16, 0, 0);
}

// ============================================================================
// Pipelined MFMA GEMM: C[M,N] = A[M,K] @ Bt[N,K]^T + bias. Tile 128x128, BK=64.
// Depth-1 prefetch with counted vmcnt (T3/T4): B (and A for AMODE=0) LDS-dbuf,
// A-reg loads for t+1 issued during t. One wait+barrier pair per K-step.
// AMODE: 0 = A bf16 (dbuf async); 1 = A f32 reg-staged; 2 = f32 + A2 add.
// CMODE: 0 = f32 out; 1 = bf16 out; 2 = bf16 transposed vt layout.
// ============================================================================
template<int AMODE, bool RELU, int CMODE>
__global__ __launch_bounds__(256) void mgemm(const void* __restrict__ Av,
                                             const float* __restrict__ A2,
                                             const unsigned short* __restrict__ Bt,
                                             const float* __restrict__ bias,
                                             float* __restrict__ Cf,
                                             unsigned short* __restrict__ Cb,
                                             int M, int N, int K)
{
    __shared__ __align__(16) unsigned short sA[(AMODE == 0 ? 2 : 1) * 128 * 64];
    __shared__ __align__(16) unsigned short sB[2 * 128 * 64];
    const int tid = threadIdx.x;
    const int w = tid >> 6, l = tid & 63;
    const int n0 = blockIdx.x * 128, m0 = blockIdx.y * 128;
    const int wr = w >> 1, wc = w & 1;
    const int nk = K >> 6;

    const unsigned short* Ab = (const unsigned short*)Av;
    const float* Af = (const float*)Av;

    f32x4 acc[4][4];
    #pragma unroll
    for (int i = 0; i < 4; i++)
        #pragma unroll
        for (int j = 0; j < 4; j++)
            #pragma unroll
            for (int r = 0; r < 4; r++) acc[i][j][r] = 0.f;

    float4 fr[8];    // raw A staging regs (AMODE 1/2)
    float4 f2[8];    // raw A2 staging regs (AMODE 2)

    auto issueB = [&](int t, unsigned short* sBb) {
        #pragma unroll
        for (int r = 0; r < 4; r++) {
            int boff = ((r * 4 + w) * 64 + l) * 16;
            int row  = boff >> 7;
            int kb   = (boff & 127) ^ ((row & 7) << 4);
            async_copy16(Bt + (size_t)(n0 + row) * K + t * 64 + (kb >> 1),
                         sBb + (size_t)(r * 4 + w) * 512);
        }
    };
    auto issueA0 = [&](int t, unsigned short* sAb) {
        #pragma unroll
        for (int r = 0; r < 4; r++) {
            int boff = ((r * 4 + w) * 64 + l) * 16;
            int row  = boff >> 7;
            int kb   = (boff & 127) ^ ((row & 7) << 4);
            int grow = m0 + row; if (grow > M - 1) grow = M - 1;
            async_copy16(Ab + (size_t)grow * K + t * 64 + (kb >> 1),
                         sAb + (size_t)(r * 4 + w) * 512);
        }
    };
    auto loadA = [&](int t) {
        #pragma unroll
        for (int r = 0; r < 4; r++) {
            int g = r * 256 + tid;
            int row = g >> 3;
            int ko  = (g & 7) * 8;
            int grow = m0 + row; if (grow > M - 1) grow = M - 1;
            const float* ap = Af + (size_t)grow * K + t * 64 + ko;
            fr[r * 2]     = *reinterpret_cast<const float4*>(ap);
            fr[r * 2 + 1] = *reinterpret_cast<const float4*>(ap + 4);
            if constexpr (AMODE == 2) {
                const float* a2 = A2 + (size_t)grow * K + t * 64 + ko;
                f2[r * 2]     = *reinterpret_cast<const float4*>(a2);
                f2[r * 2 + 1] = *reinterpret_cast<const float4*>(a2 + 4);
            }
        }
    };
    auto writeA = [&]() {
        #pragma unroll
        for (int r = 0; r < 4; r++) {
            int g = r * 256 + tid;
            int row = g >> 3;
            int ko  = (g & 7) * 8;
            float4 a0 = fr[r * 2], a1 = fr[r * 2 + 1];
            if constexpr (AMODE == 2) {
                float4 b0 = f2[r * 2], b1 = f2[r * 2 + 1];
                a0.x += b0.x; a0.y += b0.y; a0.z += b0.z; a0.w += b0.w;
                a1.x += b1.x; a1.y += b1.y; a1.z += b1.z; a1.w += b1.w;
            }
            bf16x8 pk;
            pk[0] = (short)f32_to_bf16_bits(a0.x); pk[1] = (short)f32_to_bf16_bits(a0.y);
            pk[2] = (short)f32_to_bf16_bits(a0.z); pk[3] = (short)f32_to_bf16_bits(a0.w);
            pk[4] = (short)f32_to_bf16_bits(a1.x); pk[5] = (short)f32_to_bf16_bits(a1.y);
            pk[6] = (short)f32_to_bf16_bits(a1.z); pk[7] = (short)f32_to_bf16_bits(a1.w);
            int sw = (ko * 2) ^ ((row & 7) << 4);
            *reinterpret_cast<bf16x8*>(&sA[row * 64 + (sw >> 1)]) = pk;
        }
    };

    // ---- prologue ----
    if constexpr (AMODE == 0) {
        issueA0(0, sA);
        issueB(0, sB);
    } else {
        loadA(0);
        issueB(0, sB);
    }

    for (int t = 0; t < nk; t++) {
        unsigned short* sAc = (AMODE == 0) ? (sA + (size_t)(t & 1) * 8192) : sA;
        unsigned short* sBc = sB + (size_t)(t & 1) * 8192;
        unsigned short* sAn = sA + (size_t)((t + 1) & 1) * 8192;
        unsigned short* sBn = sB + (size_t)((t + 1) & 1) * 8192;

        if constexpr (AMODE != 0) writeA();   // stage tile t into sA (regs prefetched)

        if (t + 1 < nk) {
            if constexpr (AMODE == 0) {
                issueA0(t + 1, sAn);
                issueB(t + 1, sBn);
                WAITBAR(8);                    // A(t+1)4 + B(t+1)4 newer than tile-t asyncs
            } else if constexpr (AMODE == 1) {
                issueB(t + 1, sBn);
                loadA(t + 1);
                WAITBAR(12);                   // B(t+1)4 + Aregs(t+1)8
            } else {
                issueB(t + 1, sBn);
                loadA(t + 1);
                WAITBAR(20);                   // B(t+1)4 + Aregs(t+1)16
            }
        } else {
            WAITBAR(0);
        }

        // ---- compute tile t ----
        #pragma unroll
        for (int kk = 0; kk < 2; kk++) {
            bf16x8 afr[4], bfr[4];
            const int kbyte = kk * 64 + ((l >> 4) << 4);
            #pragma unroll
            for (int mi = 0; mi < 4; mi++) {
                int row = wr * 64 + mi * 16 + (l & 15);
                int sw = kbyte ^ ((row & 7) << 4);
                afr[mi] = *reinterpret_cast<const bf16x8*>(&sAc[row * 64 + (sw >> 1)]);
            }
            #pragma unroll
            for (int ni = 0; ni < 4; ni++) {
                int row = wc * 64 + ni * 16 + (l & 15);
                int sw = kbyte ^ ((row & 7) << 4);
                bfr[ni] = *reinterpret_cast<const bf16x8*>(&sBc[row * 64 + (sw >> 1)]);
            }
            #pragma unroll
            for (int mi = 0; mi < 4; mi++)
                #pragma unroll
                for (int ni = 0; ni < 4; ni++)
                    acc[mi][ni] = __builtin_amdgcn_mfma_f32_16x16x32_bf16(
                        afr[mi], bfr[ni], acc[mi][ni], 0, 0, 0);
        }
        ENDBAR();
    }

    // ---- epilogue ----
    #pragma unroll
    for (int mi = 0; mi < 4; mi++) {
        #pragma unroll
        for (int ni = 0; ni < 4; ni++) {
            int col = n0 + wc * 64 + ni * 16 + (l & 15);
            float bz = bias[col];
            if constexpr (CMODE == 2) {
                int row0 = m0 + wr * 64 + mi * 16 + ((l >> 4) << 2);
                if (row0 + 3 < M) {
                    int bb = row0 / 1000;
                    int key = row0 - bb * 1000;
                    ushort4 q4;
                    q4.x = f32_to_bf16_bits(acc[mi][ni][0] + bz);
                    q4.y = f32_to_bf16_bits(acc[mi][ni][1] + bz);
                    q4.z = f32_to_bf16_bits(acc[mi][ni][2] + bz);
                    q4.w = f32_to_bf16_bits(acc[mi][ni][3] + bz);
                    *reinterpret_cast<ushort4*>(Cb + (size_t)bb * 262144 + (size_t)col * 1024 + key) = q4;
                }
            } else {
                #pragma unroll
                for (int rg = 0; rg < 4; rg++) {
                    int row = m0 + wr * 64 + mi * 16 + ((l >> 4) << 2) + rg;
                    if (row < M) {
                        float v = acc[mi][ni][rg] + bz;
                        if (RELU) v = fmaxf(v, 0.f);
                        if constexpr (CMODE == 1)
                            Cb[(size_t)row * N + col] = f32_to_bf16_bits(v);
                        else
                            Cf[(size_t)row * N + col] = v;
                    }
                }
            }
        }
    }
}

// ============================================================================
// Weight transpose + bf16 convert (LDS tile transpose, coalesced both sides)
// ============================================================================
struct WJobs {
    const float* src[10];
    unsigned short* dst[10];
    int K[10], N[10];
};
__global__ __launch_bounds__(256) void wconv_k(WJobs j)
{
    const int job = blockIdx.y;
    const int K = j.K[job], N = j.N[job];
    const int tilesN = N >> 6;
    const int ntiles = (K >> 6) * tilesN;
    const int tile = blockIdx.x;
    if (tile >= ntiles) return;
    const int kt = tile / tilesN, nt = tile - kt * tilesN;
    const int k0 = kt * 64, n0 = nt * 64;
    __shared__ unsigned short t_[64][65];
    const float* src = j.src[job];
    unsigned short* dst = j.dst[job];
    const int cc = threadIdx.x & 63, rr = threadIdx.x >> 6;
    #pragma unroll
    for (int i = 0; i < 16; i++) {
        int k = i * 4 + rr;
        t_[k][cc] = f32_to_bf16_bits(src[(size_t)(k0 + k) * N + n0 + cc]);
    }
    __syncthreads();
    #pragma unroll
    for (int i = 0; i < 16; i++) {
        int n = i * 4 + rr;
        dst[(size_t)(n0 + n) * K + k0 + cc] = t_[cc][n];
    }
}

__global__ __launch_bounds__(1024) void biaspack_k(const float* bq, const float* bk,
                                                   const float* boff, const float* battn,
                                                   float* qkb, float* oab)
{
    int t = threadIdx.x;
    if (t < 256)      qkb[t] = bq[t];
    else if (t < 512) qkb[t] = bk[t - 256];
    else if (t < 768) oab[t - 512] = boff[t - 512];
    else if (t < 896) oab[t - 512] = battn[t - 768];
}

// ============================================================================
// MFMA flash self-attention, K/V double-buffered, 1 barrier per kv-tile.
// qk: bf16 [NTOK][512]; vt: bf16 [B][256][1024]. Swapped S^T = mfma(K, Q).
// ============================================================================
__global__ __launch_bounds__(256) void fattn_k(const unsigned short* __restrict__ qk,
                                               const unsigned short* __restrict__ vt,
                                               unsigned short* __restrict__ sa)
{
    const int b = blockIdx.z, h = blockIdx.y;
    const int tid = threadIdx.x;
    const int w = tid >> 6, l = tid & 63;
    const int lq = l & 15, g = l >> 4;
    const int q0 = blockIdx.x * 64 + w * 16;

    __shared__ __align__(16) unsigned short Ks[2][128 * 32];   // 16 KB
    __shared__ __align__(16) unsigned short Vs[2][32 * 128];   // 16 KB
    __shared__ __align__(16) unsigned short Ps[4][16 * 128];   // 16 KB

    int qrow = q0 + lq; if (qrow > NQ_ - 1) qrow = NQ_ - 1;
    const bf16x8 qfrag = *reinterpret_cast<const bf16x8*>(
        qk + ((size_t)(b * NQ_ + qrow)) * 512 + h * 32 + g * 8);

    f32x4 O0 = {0.f, 0.f, 0.f, 0.f}, O1 = {0.f, 0.f, 0.f, 0.f};
    float m = -1e30f, lsum = 0.f;
    const float scale = 0.17677669529663687f;

    const size_t kbase = (size_t)b * (NQ_ * 512) + 256 + h * 32;
    const size_t vbase = (size_t)b * 262144 + (size_t)(h * 32) * 1024;
    const int swz = (lq & 7) << 4;

    auto issueKV = [&](int kt, int buf) {
        #pragma unroll
        for (int r = 0; r < 2; r++) {
            int lin = (r * 256 + tid) * 16;
            int krow = lin >> 6;
            int kb = (lin & 63) ^ ((krow & 7) << 4);
            async_copy16(qk + kbase + (size_t)(kt * 128 + krow) * 512 + (kb >> 1),
                         (char*)Ks[buf] + lin);
            int d = lin >> 8;
            int vb = (lin & 255) ^ ((d & 7) << 4);
            async_copy16(vt + vbase + (size_t)d * 1024 + kt * 128 + (vb >> 1),
                         (char*)Vs[buf] + lin);
        }
    };

    issueKV(0, 0);

    for (int kt = 0; kt < 8; kt++) {
        const int k0 = kt * 128;
        const int cur = kt & 1;
        asm volatile("s_waitcnt vmcnt(0) lgkmcnt(0)\n\ts_barrier" ::: "memory");
        if (kt < 7) issueKV(kt + 1, cur ^ 1);

        const unsigned short* Kc = Ks[cur];
        const unsigned short* Vc = Vs[cur];

        // ---- S^T = K @ Q^T ----
        float t[8][4];
        float tmax = -1e30f;
        const bool tail = (k0 + 128 > NQ_);
        #pragma unroll
        for (int ni = 0; ni < 8; ni++) {
            int row = ni * 16 + lq;
            bf16x8 kf = *reinterpret_cast<const bf16x8*>(
                (const char*)Kc + row * 64 + ((g * 16) ^ swz));
            f32x4 st = __builtin_amdgcn_mfma_f32_16x16x32_bf16(
                kf, qfrag, (f32x4){0.f, 0.f, 0.f, 0.f}, 0, 0, 0);
            #pragma unroll
            for (int rg = 0; rg < 4; rg++) {
                float tv = st[rg] * scale;
                if (tail) {
                    int key = k0 + ni * 16 + g * 4 + rg;
                    tv = (key < NQ_) ? tv : -1e30f;
                }
                t[ni][rg] = tv;
                tmax = fmaxf(tmax, tv);
            }
        }
        tmax = fmaxf(tmax, __shfl_xor(tmax, 16));
        tmax = fmaxf(tmax, __shfl_xor(tmax, 32));
        float mnew = fmaxf(m, tmax);
        float corr = __expf(m - mnew);
        m = mnew;

        float rs = 0.f;
        unsigned int pk[8][2];
        #pragma unroll
        for (int ni = 0; ni < 8; ni++) {
            float p0 = __expf(t[ni][0] - mnew);
            float p1 = __expf(t[ni][1] - mnew);
            float p2 = __expf(t[ni][2] - mnew);
            float p3 = __expf(t[ni][3] - mnew);
            rs += (p0 + p1) + (p2 + p3);
            pk[ni][0] = ((unsigned)f32_to_bf16_bits(p0)) | (((unsigned)f32_to_bf16_bits(p1)) << 16);
            pk[ni][1] = ((unsigned)f32_to_bf16_bits(p2)) | (((unsigned)f32_to_bf16_bits(p3)) << 16);
        }
        rs += __shfl_xor(rs, 16);
        rs += __shfl_xor(rs, 32);
        lsum = lsum * corr + rs;

        float c0 = __shfl(corr, g * 4 + 0);
        float c1 = __shfl(corr, g * 4 + 1);
        float c2 = __shfl(corr, g * 4 + 2);
        float c3 = __shfl(corr, g * 4 + 3);
        O0[0] *= c0; O0[1] *= c1; O0[2] *= c2; O0[3] *= c3;
        O1[0] *= c0; O1[1] *= c1; O1[2] *= c2; O1[3] *= c3;

        // ---- P^T -> per-wave LDS in A-frag layout ----
        unsigned short* Pw = Ps[w];
        #pragma unroll
        for (int ni = 0; ni < 8; ni++) {
            int byteoff = lq * 256 + ((ni * 32 + g * 8) ^ swz);
            *reinterpret_cast<uint2*>((char*)Pw + byteoff) = make_uint2(pk[ni][0], pk[ni][1]);
        }

        // ---- O += P @ V ----
        #pragma unroll
        for (int c = 0; c < 4; c++) {
            int rb = (c * 64 + g * 16) ^ swz;
            bf16x8 pa = *reinterpret_cast<const bf16x8*>((const char*)Pw + lq * 256 + rb);
            bf16x8 v0 = *reinterpret_cast<const bf16x8*>((const char*)Vc + lq * 256 + rb);
            bf16x8 v1 = *reinterpret_cast<const bf16x8*>((const char*)Vc + (16 + lq) * 256 + rb);
            O0 = __builtin_amdgcn_mfma_f32_16x16x32_bf16(pa, v0, O0, 0, 0, 0);
            O1 = __builtin_amdgcn_mfma_f32_16x16x32_bf16(pa, v1, O1, 0, 0, 0);
        }
    }

    float linv = 1.f / lsum;
    float i0 = __shfl(linv, g * 4 + 0);
    float i1 = __shfl(linv, g * 4 + 1);
    float i2 = __shfl(linv, g * 4 + 2);
    float i3 = __shfl(linv, g * 4 + 3);
    float iv[4] = {i0, i1, i2, i3};
    #pragma unroll
    for (int rg = 0; rg < 4; rg++) {
        int qg = q0 + g * 4 + rg;
        if (qg < NQ_) {
            size_t obase = ((size_t)(b * NQ_ + qg)) * 256 + h * 32;
            sa[obase + lq]      = f32_to_bf16_bits(O0[rg] * iv[rg]);
            sa[obase + 16 + lq] = f32_to_bf16_bits(O1[rg] * iv[rg]);
        }
    }
}

// ============================================================================
// LayerNorm: out = LN(a + b) * g + be, rows of 256
// ============================================================================
__global__ __launch_bounds__(256) void ln_k(const float* __restrict__ a,
                                            const float* __restrict__ bsum,
                                            const float* __restrict__ g,
                                            const float* __restrict__ be,
                                            float* __restrict__ out)
{
    const int wave = threadIdx.x >> 6, lane = threadIdx.x & 63;
    const int row = blockIdx.x * 4 + wave;
    float4 xa = reinterpret_cast<const float4*>(a + (size_t)row * 256)[lane];
    float4 xb = reinterpret_cast<const float4*>(bsum + (size_t)row * 256)[lane];
    float4 x = {xa.x + xb.x, xa.y + xb.y, xa.z + xb.z, xa.w + xb.w};
    float s  = x.x + x.y + x.z + x.w;
    float ss = x.x * x.x + x.y * x.y + x.z * x.z + x.w * x.w;
    #pragma unroll
    for (int off = 32; off > 0; off >>= 1) {
        s  += __shfl_xor(s, off);
        ss += __shfl_xor(ss, off);
    }
    float mu  = s * (1.f / 256.f);
    float var = ss * (1.f / 256.f) - mu * mu;
    float rstd = rsqrtf(var + 1e-5f);
    float4 gv = reinterpret_cast<const float4*>(g)[lane];
    float4 bv = reinterpret_cast<const float4*>(be)[lane];
    float4 o = {(x.x - mu) * rstd * gv.x + bv.x,
                (x.y - mu) * rstd * gv.y + bv.y,
                (x.z - mu) * rstd * gv.z + bv.z,
                (x.w - mu) * rstd * gv.w + bv.w};
    reinterpret_cast<float4*>(out + (size_t)row * 256)[lane] = o;
}

// ============================================================================
// Deformable sampling: 2 tokens/block, 2 channels/thread (4B gathers).
// ============================================================================
__device__ inline unsigned int samp2(const unsigned short* __restrict__ v,
                                     int b, int st, int Wl, int Hl,
                                     int x, int y, int hc)
{
    bool valid = (x >= 0) & (x < Wl) & (y >= 0) & (y < Hl);
    int xc = min(max(x, 0), Wl - 1);
    int yc = min(max(y, 0), Hl - 1);
    size_t idx = ((size_t)(b * S_ + st + yc * Wl + xc)) * 256 + hc;
    unsigned int val = *reinterpret_cast<const unsigned int*>(v + idx);
    return valid ? val : 0u;
}

__global__ __launch_bounds__(256) void deform_k(const float* __restrict__ rp,
                                                const float* __restrict__ oa,
                                                const unsigned short* __restrict__ value,
                                                unsigned short* __restrict__ ca)
{
    const int tk = threadIdx.x >> 7;
    const int tok = blockIdx.x * 2 + tk;
    const int b = tok / NQ_;
    const int h = (threadIdx.x >> 4) & 7;
    const int cp = threadIdx.x & 15;
    const int hc = h * 32 + cp * 2;

    const float* awp = oa + (size_t)tok * 384 + 256 + h * 16;
    float w[16];
    float mx = -1e30f;
    #pragma unroll
    for (int i = 0; i < 16; i++) { w[i] = awp[i]; mx = fmaxf(mx, w[i]); }
    float sum = 0.f;
    #pragma unroll
    for (int i = 0; i < 16; i++) { w[i] = __expf(w[i] - mx); sum += w[i]; }
    const float inv = 1.f / sum;

    const float* rpp  = rp + (size_t)tok * (L_ * 4);
    const float* offp = oa + (size_t)tok * 384 + h * 32;

    const int lvlW[4] = {128, 64, 32, 16};
    const int lvlS[4] = {0, 16384, 20480, 21504};

    float acc0 = 0.f, acc1 = 0.f;
    #pragma unroll
    for (int l = 0; l < 4; l++) {
        const int Wl = lvlW[l], Hl = lvlW[l], st = lvlS[l];
        const float cx = rpp[l * 4 + 0], cy = rpp[l * 4 + 1];
        const float cw = rpp[l * 4 + 2], chh = rpp[l * 4 + 3];
        #pragma unroll
        for (int p = 0; p < 4; p++) {
            float ox = offp[l * 8 + p * 2 + 0];
            float oy = offp[l * 8 + p * 2 + 1];
            float lx = (cx + ox * 0.25f * cw * 0.5f) * Wl - 0.5f;
            float ly = (cy + oy * 0.25f * chh * 0.5f) * Hl - 0.5f;
            float x0f = floorf(lx), y0f = floorf(ly);
            float tx = lx - x0f, ty = ly - y0f;
            int x0 = (int)x0f, y0 = (int)y0f;
            unsigned int u00 = samp2(value, b, st, Wl, Hl, x0,     y0,     hc);
            unsigned int u01 = samp2(value, b, st, Wl, Hl, x0 + 1, y0,     hc);
            unsigned int u10 = samp2(value, b, st, Wl, Hl, x0,     y0 + 1, hc);
            unsigned int u11 = samp2(value, b, st, Wl, Hl, x0 + 1, y0 + 1, hc);
            float w00 = (1.f - tx) * (1.f - ty), w01 = tx * (1.f - ty);
            float w10 = (1.f - tx) * ty,         w11 = tx * ty;
            float g0 = bf16_bits_to_f32((unsigned short)u00) * w00
                     + bf16_bits_to_f32((unsigned short)u01) * w01
                     + bf16_bits_to_f32((unsigned short)u10) * w10
                     + bf16_bits_to_f32((unsigned short)u11) * w11;
            float g1 = bf16_bits_to_f32((unsigned short)(u00 >> 16)) * w00
                     + bf16_bits_to_f32((unsigned short)(u01 >> 16)) * w01
                     + bf16_bits_to_f32((unsigned short)(u10 >> 16)) * w10
                     + bf16_bits_to_f32((unsigned short)(u11 >> 16)) * w11;
            float wa = w[l * 4 + p] * inv;
            acc0 += wa * g0;
            acc1 += wa * g1;
        }
    }
    unsigned int packed = ((unsigned)f32_to_bf16_bits(acc0)) | (((unsigned)f32_to_bf16_bits(acc1)) << 16);
    *reinterpret_cast<unsigned int*>(ca + (size_t)tok * 256 + hc) = packed;
}

// ============================================================================
extern "C" void kernel_launch(void* const* d_in, const int* in_sizes, int n_in,
                              void* d_out, int out_size, void* d_ws, size_t ws_size,
                              hipStream_t stream)
{
    const float* query      = (const float*)d_in[0];
    const float* query_pos  = (const float*)d_in[1];
    const float* ref_pts    = (const float*)d_in[2];
    const float* input_flat = (const float*)d_in[3];
    const float* Wq = (const float*)d_in[6];  const float* bq = (const float*)d_in[7];
    const float* Wk = (const float*)d_in[8];  const float* bk = (const float*)d_in[9];
    const float* Wv = (const float*)d_in[10]; const float* bv = (const float*)d_in[11];
    const float* Wo = (const float*)d_in[12]; const float* bo = (const float*)d_in[13];
    const float* ln1g = (const float*)d_in[14]; const float* ln1b = (const float*)d_in[15];
    const float* W_off = (const float*)d_in[16]; const float* b_off = (const float*)d_in[17];
    const float* W_attn = (const float*)d_in[18]; const float* b_attn = (const float*)d_in[19];
    const float* W_val = (const float*)d_in[20]; const float* b_val = (const float*)d_in[21];
    const float* W_cout = (const float*)d_in[22]; const float* b_cout = (const float*)d_in[23];
    const float* ln2g = (const float*)d_in[24]; const float* ln2b = (const float*)d_in[25];
    const float* W1 = (const float*)d_in[26]; const float* b1 = (const float*)d_in[27];
    const float* W2 = (const float*)d_in[28]; const float* b2 = (const float*)d_in[29];
    const float* ln3g = (const float*)d_in[30]; const float* ln3b = (const float*)d_in[31];
    float* out = (float*)d_out;

    // ---- workspace arena ----
    char* base = (char*)d_ws;
    size_t off = 0;
    auto alloc = [&](size_t bytes) { void* p = base + off; off += (bytes + 255) & ~(size_t)255; return p; };
    unsigned short* value_bf = (unsigned short*)alloc((size_t)B_ * S_ * 256 * 2);   // 89.1 MB
    unsigned short* qk_bf = (unsigned short*)alloc((size_t)NTOK * 1024 * 2);        // qk ∪ h_bf
    unsigned short* h_bf = qk_bf;
    unsigned short* vt = (unsigned short*)alloc((size_t)B_ * 256 * 1024 * 2);       // 4.2 MB
    float* oa_buf = (float*)alloc((size_t)NTOK * 384 * 4);
    float* tmp0   = (float*)alloc((size_t)NTOK * 256 * 4);
    float* x1     = (float*)alloc((size_t)NTOK * 256 * 4);
    float* x2     = (float*)alloc((size_t)NTOK * 256 * 4);
    unsigned short* sc_bf = (unsigned short*)alloc((size_t)NTOK * 256 * 2);
    unsigned short* wqk   = (unsigned short*)alloc(512 * 256 * 2);
    unsigned short* wv    = (unsigned short*)alloc(256 * 256 * 2);
    unsigned short* wo    = (unsigned short*)alloc(256 * 256 * 2);
    unsigned short* woa   = (unsigned short*)alloc(384 * 256 * 2);
    unsigned short* wval  = (unsigned short*)alloc(256 * 256 * 2);
    unsigned short* wcout = (unsigned short*)alloc(256 * 256 * 2);
    unsigned short* w1t   = (unsigned short*)alloc(1024 * 256 * 2);
    unsigned short* w2t   = (unsigned short*)alloc(256 * 1024 * 2);
    float* qkbias = (float*)alloc(512 * 4);
    float* oabias = (float*)alloc(384 * 4);

    dim3 blk(256);

    // ---- weight prep ----
    WJobs wj;
    wj.src[0] = Wq;    wj.dst[0] = wqk;               wj.K[0] = 256;  wj.N[0] = 256;
    wj.src[1] = Wk;    wj.dst[1] = wqk + 256 * 256;   wj.K[1] = 256;  wj.N[1] = 256;
    wj.src[2] = Wv;    wj.dst[2] = wv;                wj.K[2] = 256;  wj.N[2] = 256;
    wj.src[3] = Wo;    wj.dst[3] = wo;                wj.K[3] = 256;  wj.N[3] = 256;
    wj.src[4] = W_off; wj.dst[4] = woa;               wj.K[4] = 256;  wj.N[4] = 256;
    wj.src[5] = W_attn;wj.dst[5] = woa + 256 * 256;   wj.K[5] = 256;  wj.N[5] = 128;
    wj.src[6] = W_val; wj.dst[6] = wval;              wj.K[6] = 256;  wj.N[6] = 256;
    wj.src[7] = W_cout;wj.dst[7] = wcout;             wj.K[7] = 256;  wj.N[7] = 256;
    wj.src[8] = W1;    wj.dst[8] = w1t;               wj.K[8] = 256;  wj.N[8] = 1024;
    wj.src[9] = W2;    wj.dst[9] = w2t;               wj.K[9] = 1024; wj.N[9] = 256;
    wconv_k<<<dim3(64, 10), blk, 0, stream>>>(wj);
    biaspack_k<<<1, 1024, 0, stream>>>(bq, bk, b_off, b_attn, qkbias, oabias);

    // ---- self-attention block ----
    mgemm<2, false, 1><<<dim3(4, 63), blk, 0, stream>>>(query, query_pos, wqk, qkbias, nullptr, qk_bf, NTOK, 512, 256);
    mgemm<1, false, 2><<<dim3(2, 63), blk, 0, stream>>>(query, nullptr,   wv,  bv,     nullptr, vt,    NTOK, 256, 256);
    fattn_k<<<dim3(16, NH_, B_), blk, 0, stream>>>(qk_bf, vt, sc_bf);
    mgemm<0, false, 0><<<dim3(2, 63), blk, 0, stream>>>(sc_bf, nullptr, wo, bo, tmp0, nullptr, NTOK, 256, 256);
    ln_k<<<NTOK / 4, blk, 0, stream>>>(query, tmp0, ln1g, ln1b, x1);

    // ---- deformable cross-attention ----
    mgemm<1, false, 1><<<dim3(2, 1360), blk, 0, stream>>>(input_flat, nullptr, wval, b_val, nullptr, value_bf, B_ * S_, 256, 256);
    mgemm<2, false, 0><<<dim3(3, 63),  blk, 0, stream>>>(x1, query_pos, woa, oabias, oa_buf, nullptr, NTOK, 384, 256);
    deform_k<<<NTOK / 2, blk, 0, stream>>>(ref_pts, oa_buf, value_bf, sc_bf);
    mgemm<0, false, 0><<<dim3(2, 63), blk, 0, stream>>>(sc_bf, nullptr, wcout, b_cout, tmp0, nullptr, NTOK, 256, 256);
    ln_k<<<NTOK / 4, blk, 0, stream>>>(x1, tmp0, ln2g, ln2b, x2);

    // ---- FFN ----
    mgemm<1, true,  1><<<dim3(8, 63), blk, 0, stream>>>(x2, nullptr, w1t, b1, nullptr, h_bf, NTOK, DFF_, 256);
    mgemm<0, false, 0><<<dim3(2, 63), blk, 0, stream>>>(h_bf, nullptr, w2t, b2, tmp0, nullptr, NTOK, 256, DFF_);
    ln_k<<<NTOK / 4, blk, 0, stream>>>(x2, tmp0, ln3g, ln3b, out);
}